// Round 1
// 706.497 us; speedup vs baseline: 1.0161x; 1.0161x over previous
//
#include <hip/hip_runtime.h>

#define DIM 1536
#define IMG 1024
#define TXT 256
#define SEQ 1280
#define NH 24
#define HD 64
#define SD ((size_t)SEQ * DIM)
#define IDSZ ((size_t)IMG * DIM)

typedef __attribute__((ext_vector_type(8))) short short8;
typedef __attribute__((ext_vector_type(4))) float f32x4;

__device__ __forceinline__ float bf2f(ushort u) {
    union { unsigned int i; float f; } v; v.i = ((unsigned int)u) << 16; return v.f;
}
__device__ __forceinline__ ushort f2bf(float f) {
    union { unsigned int i; float f; } v; v.f = f;
    unsigned int u = v.i;
    u += 0x7fffu + ((u >> 16) & 1u);
    return (ushort)(u >> 16);
}

// ---------------------------------------------------------------------------
// Input-dtype detector (flag=1 -> fp32 underneath, flag=0 -> bf16).
// ---------------------------------------------------------------------------
__global__ __launch_bounds__(256) void detect_dtype(const void* __restrict__ p,
                                                    int* __restrict__ flag)
{
    __shared__ int cnt;
    if (threadIdx.x == 0) cnt = 0;
    __syncthreads();
    const ushort* u = (const ushort*)p;
    int local = 0;
    for (int i = threadIdx.x; i < 2048; i += 256) {
        ushort v = u[2 * i];
        int e = (v >> 7) & 0xFF;
        if (e >= 0xC0) local++;
    }
    atomicAdd(&cnt, local);
    __syncthreads();
    if (threadIdx.x == 0) flag[0] = (cnt > 16) ? 1 : 0;
}

// ---------------------------------------------------------------------------
// LDS swizzle for GEMM tiles, row stride 40 ushorts (32 data + 8 pad).
// ---------------------------------------------------------------------------
#define LSTR 40

// ===========================================================================
// Fused QKV GEMM: dbuf + prefetch. Epilogue optionally emits bf16 hi/lo split
// planes (Yh/Yl non-null) so attention can consume pre-split operands.
// ===========================================================================
struct QKVP {
    const void* Xi; const void* Xt;
    const void* W[6];   // wq,wk,wv (img), waddq,waddk,waddv (txt)
    const void* B[6];
    float* Y[3];
    ushort* Yh[3];
    ushort* Yl[3];
};

__global__ __launch_bounds__(256) void gemm_qkv_v2(QKVP p, const int* __restrict__ dflag)
{
    __shared__ __align__(16) ushort As[2][128 * LSTR];
    __shared__ __align__(16) ushort Bs[2][128 * LSTR];
    const int dt = dflag[0];
    const int bx = blockIdx.x;
    const int wsel = bx / 12;
    const int n0 = (bx - wsel * 12) * 128;
    const int m0g = blockIdx.y * 128;
    const bool istxt = (m0g >= IMG);
    const int m0 = istxt ? (m0g - IMG) : m0g;
    const void* X  = istxt ? p.Xt : p.Xi;
    const void* Wp = p.W[wsel + (istxt ? 3 : 0)];
    const void* Bp = p.B[wsel + (istxt ? 3 : 0)];
    float* Y = p.Y[wsel];

    const int t = threadIdx.x;
    const int wave = t >> 6, lane = t & 63;
    const int quad = lane >> 4, l16 = lane & 15;
    const int wm = (wave >> 1) * 64, wn = (wave & 1) * 64;

    const int arow = t >> 1, apair = t & 1;
    const int bn8 = (t & 15) << 3, bkk = (t >> 4) << 1;
    const int aps = apair ^ ((arow >> 3) & 1);
    const int adst = arow * LSTR + aps * 16;
    const int bq = bkk >> 3, bo = bkk & 7;

    f32x4 acc[4][4];
#pragma unroll
    for (int i = 0; i < 4; ++i)
#pragma unroll
        for (int j = 0; j < 4; ++j) acc[i][j] = (f32x4)(0.0f);

    float4 raf[4]; uint4 rau[2];
    float4 rbf[4]; uint4 rbu[2];

    auto loadA = [&](int k0) {
        const size_t off = (size_t)(m0 + arow) * DIM + k0 + apair * 16;
        if (dt) {
            const float* xp = (const float*)X + off;
            raf[0] = *(const float4*)xp;       raf[1] = *(const float4*)(xp + 4);
            raf[2] = *(const float4*)(xp + 8); raf[3] = *(const float4*)(xp + 12);
        } else {
            const ushort* xp = (const ushort*)X + off;
            rau[0] = *(const uint4*)xp;
            rau[1] = *(const uint4*)(xp + 8);
        }
    };
    auto loadB = [&](int k0) {
        const size_t off = (size_t)(k0 + bkk) * DIM + n0 + bn8;
        if (dt) {
            const float* wp0 = (const float*)Wp + off;
            rbf[0] = *(const float4*)wp0;         rbf[1] = *(const float4*)(wp0 + 4);
            rbf[2] = *(const float4*)(wp0 + DIM); rbf[3] = *(const float4*)(wp0 + DIM + 4);
        } else {
            const ushort* wp0 = (const ushort*)Wp + off;
            rbu[0] = *(const uint4*)wp0;
            rbu[1] = *(const uint4*)(wp0 + DIM);
        }
    };
    auto storeA = [&](int buf) {
        ushort tmp[16];
        if (dt) {
            const float* xs = (const float*)raf;
#pragma unroll
            for (int i = 0; i < 16; ++i) tmp[i] = f2bf(xs[i]);
        } else {
            *(uint4*)&tmp[0] = rau[0];
            *(uint4*)&tmp[8] = rau[1];
        }
        *(uint4*)&As[buf][adst]     = *(uint4*)&tmp[0];
        *(uint4*)&As[buf][adst + 8] = *(uint4*)&tmp[8];
    };
    auto storeB = [&](int buf) {
        ushort t0[8], t1[8];
        if (dt) {
            const float* f = (const float*)rbf;
#pragma unroll
            for (int j = 0; j < 8; ++j) { t0[j] = f2bf(f[j]); t1[j] = f2bf(f[8 + j]); }
        } else {
            *(uint4*)t0 = rbu[0];
            *(uint4*)t1 = rbu[1];
        }
#pragma unroll
        for (int j = 0; j < 8; ++j) {
            const int rr = bn8 + j;
            const int col = (((bq ^ (rr >> 3)) & 3) << 3) + bo;
            *(unsigned int*)&Bs[buf][rr * LSTR + col] =
                (unsigned int)t0[j] | ((unsigned int)t1[j] << 16);
        }
    };

    loadA(0); loadB(0);
    storeA(0); storeB(0);
    __syncthreads();

    for (int k = 0; k < DIM / 32; ++k) {
        const int cur = k & 1;
        const bool hn = (k + 1) < DIM / 32;
        if (hn) { loadA((k + 1) * 32); loadB((k + 1) * 32); }

        short8 b[4];
#pragma unroll
        for (int j = 0; j < 4; ++j) {
            const int rr = wn + j * 16 + l16;
            const int col = (((quad ^ (rr >> 3)) & 3) << 3);
            b[j] = *(const short8*)&Bs[cur][rr * LSTR + col];
        }
#pragma unroll
        for (int i = 0; i < 4; ++i) {
            const int rr = wm + i * 16 + l16;
            const int ps = (quad >> 1) ^ ((rr >> 3) & 1);
            const int col = ps * 16 + (quad & 1) * 8;
            short8 a = *(const short8*)&As[cur][rr * LSTR + col];
#pragma unroll
            for (int j = 0; j < 4; ++j)
                acc[i][j] = __builtin_amdgcn_mfma_f32_16x16x32_bf16(a, b[j], acc[i][j], 0, 0, 0);
        }
        if (hn) { storeA(cur ^ 1); storeB(cur ^ 1); }
        __syncthreads();
    }

    ushort* yh = p.Yh[wsel];
    ushort* yl = p.Yl[wsel];
#pragma unroll
    for (int j = 0; j < 4; ++j) {
        const int col = n0 + wn + j * 16 + l16;
        const float bv = dt ? ((const float*)Bp)[col] : bf2f(((const ushort*)Bp)[col]);
#pragma unroll
        for (int i = 0; i < 4; ++i)
#pragma unroll
            for (int r = 0; r < 4; ++r) {
                const int row = m0g + wm + i * 16 + quad * 4 + r;
                const size_t o = (size_t)row * DIM + col;
                const float val = acc[i][j][r] + bv;
                Y[o] = val;
                if (yh) {
                    const ushort hv = f2bf(val);
                    yh[o] = hv;
                    yl[o] = f2bf(val - bf2f(hv));
                }
            }
    }
}

// ===========================================================================
// Merged output projections (unchanged).
// ===========================================================================
struct OutP {
    const float* X;
    const void* W[4]; const void* B[4];
    void* out;
};

__global__ __launch_bounds__(256) void gemm_out_v2(OutP p, const int* __restrict__ dflag)
{
    __shared__ __align__(16) ushort Ah[2][128 * LSTR];
    __shared__ __align__(16) ushort Al[2][128 * LSTR];
    __shared__ __align__(16) ushort Bs[2][128 * LSTR];
    const int dt = dflag[0];
    const int n0 = blockIdx.x * 128;
    const int mt = blockIdx.y;
    const int seg = (mt < 8) ? 0 : (mt < 10) ? 1 : (mt < 18) ? 2 : 3;
    const void* Wp = p.W[seg];
    const void* Bp = p.B[seg];
    const int m0 = mt * 128;

    const int t = threadIdx.x;
    const int wave = t >> 6, lane = t & 63;
    const int quad = lane >> 4, l16 = lane & 15;
    const int wm = (wave >> 1) * 64, wn = (wave & 1) * 64;

    const int arow = t >> 1, apair = t & 1;
    const int bn8 = (t & 15) << 3, bkk = (t >> 4) << 1;
    const int aps = apair ^ ((arow >> 3) & 1);
    const int adst = arow * LSTR + aps * 16;
    const int bq = bkk >> 3, bo = bkk & 7;

    f32x4 acc[4][4];
#pragma unroll
    for (int i = 0; i < 4; ++i)
#pragma unroll
        for (int j = 0; j < 4; ++j) acc[i][j] = (f32x4)(0.0f);

    float4 raf[4];
    float4 rbf[4]; uint4 rbu[2];

    auto loadA = [&](int k0) {
        const float* xp = p.X + (size_t)(m0 + arow) * DIM + k0 + apair * 16;
        raf[0] = *(const float4*)xp;       raf[1] = *(const float4*)(xp + 4);
        raf[2] = *(const float4*)(xp + 8); raf[3] = *(const float4*)(xp + 12);
    };
    auto loadB = [&](int k0) {
        const size_t off = (size_t)(k0 + bkk) * DIM + n0 + bn8;
        if (dt) {
            const float* wp0 = (const float*)Wp + off;
            rbf[0] = *(const float4*)wp0;         rbf[1] = *(const float4*)(wp0 + 4);
            rbf[2] = *(const float4*)(wp0 + DIM); rbf[3] = *(const float4*)(wp0 + DIM + 4);
        } else {
            const ushort* wp0 = (const ushort*)Wp + off;
            rbu[0] = *(const uint4*)wp0;
            rbu[1] = *(const uint4*)(wp0 + DIM);
        }
    };
    auto storeA = [&](int buf) {
        ushort hi[16], lo[16];
        const float* xs = (const float*)raf;
#pragma unroll
        for (int i = 0; i < 16; ++i) {
            hi[i] = f2bf(xs[i]);
            lo[i] = f2bf(xs[i] - bf2f(hi[i]));
        }
        *(uint4*)&Ah[buf][adst]     = *(uint4*)&hi[0];
        *(uint4*)&Ah[buf][adst + 8] = *(uint4*)&hi[8];
        *(uint4*)&Al[buf][adst]     = *(uint4*)&lo[0];
        *(uint4*)&Al[buf][adst + 8] = *(uint4*)&lo[8];
    };
    auto storeB = [&](int buf) {
        ushort t0[8], t1[8];
        if (dt) {
            const float* f = (const float*)rbf;
#pragma unroll
            for (int j = 0; j < 8; ++j) { t0[j] = f2bf(f[j]); t1[j] = f2bf(f[8 + j]); }
        } else {
            *(uint4*)t0 = rbu[0];
            *(uint4*)t1 = rbu[1];
        }
#pragma unroll
        for (int j = 0; j < 8; ++j) {
            const int rr = bn8 + j;
            const int col = (((bq ^ (rr >> 3)) & 3) << 3) + bo;
            *(unsigned int*)&Bs[buf][rr * LSTR + col] =
                (unsigned int)t0[j] | ((unsigned int)t1[j] << 16);
        }
    };

    loadA(0); loadB(0);
    storeA(0); storeB(0);
    __syncthreads();

    for (int k = 0; k < DIM / 32; ++k) {
        const int cur = k & 1;
        const bool hn = (k + 1) < DIM / 32;
        if (hn) { loadA((k + 1) * 32); loadB((k + 1) * 32); }

        short8 b[4];
#pragma unroll
        for (int j = 0; j < 4; ++j) {
            const int rr = wn + j * 16 + l16;
            const int col = (((quad ^ (rr >> 3)) & 3) << 3);
            b[j] = *(const short8*)&Bs[cur][rr * LSTR + col];
        }
#pragma unroll
        for (int i = 0; i < 4; ++i) {
            const int rr = wm + i * 16 + l16;
            const int ps = (quad >> 1) ^ ((rr >> 3) & 1);
            const int col = ps * 16 + (quad & 1) * 8;
            short8 ah = *(const short8*)&Ah[cur][rr * LSTR + col];
            short8 al = *(const short8*)&Al[cur][rr * LSTR + col];
#pragma unroll
            for (int j = 0; j < 4; ++j) {
                acc[i][j] = __builtin_amdgcn_mfma_f32_16x16x32_bf16(ah, b[j], acc[i][j], 0, 0, 0);
                acc[i][j] = __builtin_amdgcn_mfma_f32_16x16x32_bf16(al, b[j], acc[i][j], 0, 0, 0);
            }
        }
        if (hn) { storeA(cur ^ 1); storeB(cur ^ 1); }
        __syncthreads();
    }

#pragma unroll
    for (int j = 0; j < 4; ++j) {
        const int col = n0 + wn + j * 16 + l16;
        const float bv = dt ? ((const float*)Bp)[col] : bf2f(((const ushort*)Bp)[col]);
#pragma unroll
        for (int i = 0; i < 4; ++i)
#pragma unroll
            for (int r = 0; r < 4; ++r) {
                const int grow = m0 + wm + i * 16 + quad * 4 + r;
                const size_t o = (size_t)grow * DIM + col;
                const float val = acc[i][j][r] + bv;
                if (dt) ((float*)p.out)[o] = val;
                else    ((ushort*)p.out)[o] = f2bf(val);
            }
    }
}

// ---------------------------------------------------------------------------
// RoPE kernels. pe flat layout: s*128 + i*4 + {cos,-sin,sin,cos}.
// Outputs go straight to bf16 hi/lo split planes (attention's input format).
// ---------------------------------------------------------------------------
__device__ __forceinline__ void pe_load(const void* pe, int dt, size_t off,
                                        float& c00, float& c01, float& c10, float& c11)
{
    if (dt) {
        float4 pv = *(const float4*)((const float*)pe + off);
        c00 = pv.x; c01 = pv.y; c10 = pv.z; c11 = pv.w;
    } else {
        const ushort* pp = (const ushort*)pe + off;
        c00 = bf2f(pp[0]); c01 = bf2f(pp[1]); c10 = bf2f(pp[2]); c11 = bf2f(pp[3]);
    }
}

__global__ __launch_bounds__(256) void rope_f32_to_split(
    const float* __restrict__ src, const void* __restrict__ pe,
    ushort* __restrict__ dh, ushort* __restrict__ dl,
    const int* __restrict__ dflag, int S)
{
    const int dt = dflag[0];
    int idx = blockIdx.x * 256 + threadIdx.x;
    if (idx >= S * 768) return;
    int s = idx / 768, pp = idx - s * 768;
    int col = pp << 1, i = pp & 31;
    float2 xv = *(const float2*)(src + (size_t)s * DIM + col);
    float c00, c01, c10, c11;
    pe_load(pe, dt, (size_t)s * 128 + i * 4, c00, c01, c10, c11);
    float y0 = c00 * xv.x + c01 * xv.y;
    float y1 = c10 * xv.x + c11 * xv.y;
    ushort h0 = f2bf(y0), h1 = f2bf(y1);
    ushort l0 = f2bf(y0 - bf2f(h0)), l1 = f2bf(y1 - bf2f(h1));
    *(unsigned int*)(dh + (size_t)s * DIM + col) = (unsigned int)h0 | ((unsigned int)h1 << 16);
    *(unsigned int*)(dl + (size_t)s * DIM + col) = (unsigned int)l0 | ((unsigned int)l1 << 16);
}

__global__ __launch_bounds__(256) void rope_in_to_split(
    const void* __restrict__ src, const void* __restrict__ pe,
    ushort* __restrict__ dh, ushort* __restrict__ dl,
    const int* __restrict__ dflag, int S)
{
    const int dt = dflag[0];
    int idx = blockIdx.x * 256 + threadIdx.x;
    if (idx >= S * 768) return;
    int s = idx / 768, pp = idx - s * 768;
    int col = pp << 1, i = pp & 31;
    float x0, x1;
    if (dt) {
        float2 xv = *(const float2*)((const float*)src + (size_t)s * DIM + col);
        x0 = xv.x; x1 = xv.y;
    } else {
        const ushort* sp = (const ushort*)src + (size_t)s * DIM + col;
        x0 = bf2f(sp[0]); x1 = bf2f(sp[1]);
    }
    float c00, c01, c10, c11;
    pe_load(pe, dt, (size_t)s * 128 + i * 4, c00, c01, c10, c11);
    float y0 = c00 * x0 + c01 * x1;
    float y1 = c10 * x0 + c11 * x1;
    ushort h0 = f2bf(y0), h1 = f2bf(y1);
    ushort l0 = f2bf(y0 - bf2f(h0)), l1 = f2bf(y1 - bf2f(h1));
    *(unsigned int*)(dh + (size_t)s * DIM + col) = (unsigned int)h0 | ((unsigned int)h1 << 16);
    *(unsigned int*)(dl + (size_t)s * DIM + col) = (unsigned int)l0 | ((unsigned int)l1 << 16);
}

// ---------------------------------------------------------------------------
// V transpose+split: f32 [seq][DIM] -> hi/lo bf16 [h*64+d][seq].
// LDS tile transpose: packed hi|lo u32 tile [64][65] (stride 65 -> 2-way free).
// ---------------------------------------------------------------------------
__global__ __launch_bounds__(256) void vtrans_split(
    const float* __restrict__ V, ushort* __restrict__ Vth, ushort* __restrict__ Vtl,
    int seq)
{
    __shared__ unsigned int tile[64 * 65];
    const int s0 = blockIdx.x * 64;
    const int h = blockIdx.y;
    const int t = threadIdx.x;
#pragma unroll
    for (int it = 0; it < 16; ++it) {
        const int sl = (t >> 6) + (it << 2);
        const int d = t & 63;
        const float v = V[(size_t)(s0 + sl) * DIM + h * HD + d];
        const ushort hv = f2bf(v);
        const ushort lv = f2bf(v - bf2f(hv));
        tile[d * 65 + sl] = (unsigned int)hv | ((unsigned int)lv << 16);
    }
    __syncthreads();
    const int d = t >> 2, cc = (t & 3) << 4;
    ushort th[16], tl[16];
#pragma unroll
    for (int j = 0; j < 16; ++j) {
        const unsigned int w = tile[d * 65 + cc + j];
        th[j] = (ushort)w;
        tl[j] = (ushort)(w >> 16);
    }
    const size_t off = (size_t)(h * HD + d) * seq + s0 + cc;
    *(uint4*)(Vth + off)     = *(uint4*)&th[0];
    *(uint4*)(Vth + off + 8) = *(uint4*)&th[8];
    *(uint4*)(Vtl + off)     = *(uint4*)&tl[0];
    *(uint4*)(Vtl + off + 8) = *(uint4*)&tl[8];
}

// ---------------------------------------------------------------------------
// MFMA flash attention, KV-split (grid.z = 2) over pre-split bf16 hi/lo
// operands. Writes unnormalized O partials + (m,l); merge kernel combines.
// ---------------------------------------------------------------------------
__device__ __forceinline__ int swz(int row, int col) {
    return row * 64 + ((((col >> 3) ^ row) & 7) << 3) + (col & 7);
}
__device__ __forceinline__ short8 ldfrag(const ushort* plane, int row, int col) {
    return *(const short8*)&plane[swz(row, col)];
}

struct AttnP {
    const ushort *Qh, *Ql, *Kh, *Kl, *Vth, *Vtl;
    float* Op;      // [2][SEQ*DIM] partials (aliases dead q1/k1 f32)
    float2* Ml;     // [2][NH][SEQ] (m,l)
    int kvchunk;    // kv positions per z-split (640)
    int kvstride;   // seq stride of Vt layout (SEQ)
};

__global__ __launch_bounds__(256) void attn_mfma_split(AttnP p)
{
    __shared__ ushort Qh_[4096], Ql_[4096];
    __shared__ ushort Kh_[4096], Kl_[4096];
    __shared__ ushort Vh_[4096], Vl_[4096];

    const int q0 = blockIdx.x * 64;
    const int h = blockIdx.y;
    const int z = blockIdx.z;
    const int t = threadIdx.x;
    const int wave = t >> 6, lane = t & 63;
    const int quad = lane >> 4, l16 = lane & 15;
    const int wq0 = wave * 16;

    const int srow = t >> 2, c0 = (t & 3) << 4;
    const int g0 = c0 >> 3;
    const int p0 = ((g0 ^ (srow & 7)) & 7) << 3;
    const int p1 = (((g0 + 1) ^ (srow & 7)) & 7) << 3;

    {
        const size_t off = (size_t)(q0 + srow) * DIM + h * HD + c0;
        *(uint4*)&Qh_[srow * 64 + p0] = *(const uint4*)(p.Qh + off);
        *(uint4*)&Qh_[srow * 64 + p1] = *(const uint4*)(p.Qh + off + 8);
        *(uint4*)&Ql_[srow * 64 + p0] = *(const uint4*)(p.Ql + off);
        *(uint4*)&Ql_[srow * 64 + p1] = *(const uint4*)(p.Ql + off + 8);
    }
    // Within-wave store->read: wave w stages rows 16w..16w+15 and reads only
    // those rows for its fragments (lgkmcnt-ordered, no barrier needed).
    short8 qfh[2], qfl[2];
#pragma unroll
    for (int c = 0; c < 2; ++c) {
        qfh[c] = ldfrag(Qh_, wq0 + l16, c * 32 + quad * 8);
        qfl[c] = ldfrag(Ql_, wq0 + l16, c * 32 + quad * 8);
    }

    float m_[4], l_[4];
#pragma unroll
    for (int r = 0; r < 4; ++r) { m_[r] = -3e38f; l_[r] = 0.0f; }
    f32x4 Oacc[4];
#pragma unroll
    for (int j = 0; j < 4; ++j) Oacc[j] = (f32x4)(0.0f);

    const int kvbeg = z * p.kvchunk;
    for (int kt = 0; kt < p.kvchunk; kt += 64) {
        const int kv0 = kvbeg + kt;
        __syncthreads();
        {
            const size_t off = (size_t)(kv0 + srow) * DIM + h * HD + c0;
            *(uint4*)&Kh_[srow * 64 + p0] = *(const uint4*)(p.Kh + off);
            *(uint4*)&Kh_[srow * 64 + p1] = *(const uint4*)(p.Kh + off + 8);
            *(uint4*)&Kl_[srow * 64 + p0] = *(const uint4*)(p.Kl + off);
            *(uint4*)&Kl_[srow * 64 + p1] = *(const uint4*)(p.Kl + off + 8);
        }
        {
            const size_t off = (size_t)(h * HD + srow) * p.kvstride + kv0 + c0;
            *(uint4*)&Vh_[srow * 64 + p0] = *(const uint4*)(p.Vth + off);
            *(uint4*)&Vh_[srow * 64 + p1] = *(const uint4*)(p.Vth + off + 8);
            *(uint4*)&Vl_[srow * 64 + p0] = *(const uint4*)(p.Vtl + off);
            *(uint4*)&Vl_[srow * 64 + p1] = *(const uint4*)(p.Vtl + off + 8);
        }
        __syncthreads();

        f32x4 S[4];
#pragma unroll
        for (int j = 0; j < 4; ++j) S[j] = (f32x4)(0.0f);
#pragma unroll
        for (int c = 0; c < 2; ++c) {
#pragma unroll
            for (int j = 0; j < 4; ++j) {
                short8 bh = ldfrag(Kh_, j * 16 + l16, c * 32 + quad * 8);
                short8 bl = ldfrag(Kl_, j * 16 + l16, c * 32 + quad * 8);
                S[j] = __builtin_amdgcn_mfma_f32_16x16x32_bf16(qfh[c], bh, S[j], 0, 0, 0);
                S[j] = __builtin_amdgcn_mfma_f32_16x16x32_bf16(qfl[c], bh, S[j], 0, 0, 0);
                S[j] = __builtin_amdgcn_mfma_f32_16x16x32_bf16(qfh[c], bl, S[j], 0, 0, 0);
            }
        }
#pragma unroll
        for (int j = 0; j < 4; ++j)
#pragma unroll
            for (int r = 0; r < 4; ++r) S[j][r] *= 0.125f;

        float alpha[4];
#pragma unroll
        for (int r = 0; r < 4; ++r) {
            float mx = fmaxf(fmaxf(S[0][r], S[1][r]), fmaxf(S[2][r], S[3][r]));
            mx = fmaxf(mx, __shfl_xor(mx, 1));
            mx = fmaxf(mx, __shfl_xor(mx, 2));
            mx = fmaxf(mx, __shfl_xor(mx, 4));
            mx = fmaxf(mx, __shfl_xor(mx, 8));
            float mn = fmaxf(m_[r], mx);
            alpha[r] = __expf(m_[r] - mn);
            m_[r] = mn;
            float rs = 0.0f;
#pragma unroll
            for (int j = 0; j < 4; ++j) {
                float pv = __expf(S[j][r] - mn);
                S[j][r] = pv;
                rs += pv;
            }
            rs += __shfl_xor(rs, 1);
            rs += __shfl_xor(rs, 2);
            rs += __shfl_xor(rs, 4);
            rs += __shfl_xor(rs, 8);
            l_[r] = l_[r] * alpha[r] + rs;
        }
#pragma unroll
        for (int j = 0; j < 4; ++j)
#pragma unroll
            for (int r = 0; r < 4; ++r) Oacc[j][r] *= alpha[r];

        {
            const int prow = wq0 + quad * 4;
#pragma unroll
            for (int j = 0; j < 4; ++j)
#pragma unroll
                for (int r = 0; r < 4; ++r) {
                    float pv = S[j][r];
                    ushort ph = f2bf(pv);
                    ushort pl = f2bf(pv - bf2f(ph));
                    int idx = swz(prow + r, j * 16 + l16);
                    Qh_[idx] = ph;
                    Ql_[idx] = pl;
                }
        }

#pragma unroll
        for (int c = 0; c < 2; ++c) {
            short8 pah = ldfrag(Qh_, wq0 + l16, c * 32 + quad * 8);
            short8 pal = ldfrag(Ql_, wq0 + l16, c * 32 + quad * 8);
#pragma unroll
            for (int jn = 0; jn < 4; ++jn) {
                short8 vbh = ldfrag(Vh_, jn * 16 + l16, c * 32 + quad * 8);
                short8 vbl = ldfrag(Vl_, jn * 16 + l16, c * 32 + quad * 8);
                Oacc[jn] = __builtin_amdgcn_mfma_f32_16x16x32_bf16(pah, vbh, Oacc[jn], 0, 0, 0);
                Oacc[jn] = __builtin_amdgcn_mfma_f32_16x16x32_bf16(pal, vbh, Oacc[jn], 0, 0, 0);
                Oacc[jn] = __builtin_amdgcn_mfma_f32_16x16x32_bf16(pah, vbl, Oacc[jn], 0, 0, 0);
            }
        }
    }

    float* Opz = p.Op + (size_t)z * SD;
#pragma unroll
    for (int r = 0; r < 4; ++r) {
        const int rowq = q0 + wq0 + quad * 4 + r;
        if (l16 == 0)
            p.Ml[((size_t)z * NH + h) * SEQ + rowq] = make_float2(m_[r], l_[r]);
#pragma unroll
        for (int jn = 0; jn < 4; ++jn)
            Opz[(size_t)rowq * DIM + h * HD + jn * 16 + l16] = Oacc[jn][r];
    }
}

// Merge NSPLIT=2 partials: O = sum_z e^{m_z-m*} O_z / sum_z e^{m_z-m*} l_z.
// Optional addto (cross-attn folds the residual add here).
__global__ __launch_bounds__(256) void attn_merge(
    const float* __restrict__ Op, const float2* __restrict__ Ml,
    float* __restrict__ out, const float* __restrict__ addto, int qlen)
{
    const int idx = blockIdx.x * 256 + threadIdx.x;
    if (idx >= qlen * 384) return;
    const int rowq = idx / 384;
    const int c4 = (idx - rowq * 384) << 2;
    const int h = c4 >> 6;
    const float2 a = Ml[(size_t)h * SEQ + rowq];
    const float2 b = Ml[(size_t)(NH + h) * SEQ + rowq];
    const float ms = fmaxf(a.x, b.x);
    const float s0 = __expf(a.x - ms), s1 = __expf(b.x - ms);
    const float inv = 1.0f / (s0 * a.y + s1 * b.y);
    const float4 o0 = *(const float4*)&Op[(size_t)rowq * DIM + c4];
    const float4 o1 = *(const float4*)&Op[SD + (size_t)rowq * DIM + c4];
    float4 r;
    r.x = (s0 * o0.x + s1 * o1.x) * inv;
    r.y = (s0 * o0.y + s1 * o1.y) * inv;
    r.z = (s0 * o0.z + s1 * o1.z) * inv;
    r.w = (s0 * o0.w + s1 * o1.w) * inv;
    if (addto) {
        const float4 c = *(const float4*)&addto[(size_t)rowq * DIM + c4];
        r.x += c.x; r.y += c.y; r.z += c.z; r.w += c.w;
    }
    *(float4*)&out[(size_t)rowq * DIM + c4] = r;
}

// ---------------------------------------------------------------------------
extern "C" void kernel_launch(void* const* d_in, const int* in_sizes, int n_in,
                              void* d_out, int out_size, void* d_ws, size_t ws_size,
                              hipStream_t stream) {
    (void)in_sizes; (void)n_in; (void)out_size; (void)ws_size;
    const void* hs   = d_in[0];
    const void* ehs  = d_in[1];
    const void* hsc  = d_in[2];
    const void* ehsc = d_in[3];
    const void* i2q  = d_in[4];
    const void* pe   = d_in[5];
#define W_(i) ((const void*)d_in[i])

    int*   flag = (int*)d_ws;
    float* fb = (float*)((char*)d_ws + 256);
    float* q1 = fb;            // SD f32 (also aliased by Op[0])
    float* k1 = q1 + SD;       // SD f32 (also aliased by Op[1])
    float* v1 = k1 + SD;       // SD f32
    float* oA = v1 + SD;       // SD f32 (out-proj X rows 0..1279)
    float* oC = oA + SD;       // SD f32 (MUST be oA+SD: out-proj X spans both)
    ushort* qh  = (ushort*)(oC + SD);  // split planes, SD ushorts each
    ushort* qlo = qh + SD;
    ushort* kh  = qlo + SD;
    ushort* klo = kh + SD;
    ushort* vth = klo + SD;
    ushort* vtl = vth + SD;
    ushort* qxh = vtl + SD;    // IDSZ ushorts
    ushort* qxl = qxh + IDSZ;
    float2* Ml = (float2*)(qxl + IDSZ);  // 2*NH*SEQ float2
    float* Op = q1;            // partial-O buffer: 2*SD f32 over dead q1+k1

    dim3 blk(256);
    detect_dtype<<<1, blk, 0, stream>>>(hs, flag);

    auto QKV = [&](const void* Xi, const void* Xt, int iw0, int itw0, bool emit_split) {
        QKVP p;
        p.Xi = Xi; p.Xt = Xt;
        for (int j = 0; j < 3; ++j) {
            p.W[j]     = W_(iw0 + 2 * j);  p.B[j]     = W_(iw0 + 2 * j + 1);
            p.W[3 + j] = W_(itw0 + 2 * j); p.B[3 + j] = W_(itw0 + 2 * j + 1);
            p.Yh[j] = nullptr; p.Yl[j] = nullptr;
        }
        p.Y[0] = q1; p.Y[1] = k1; p.Y[2] = v1;
        if (emit_split) {   // stream A: no rope -> q,k split straight from GEMM
            p.Yh[0] = qh;  p.Yl[0] = qlo;
            p.Yh[1] = kh;  p.Yl[1] = klo;
        }
        gemm_qkv_v2<<<dim3(36, 10), blk, 0, stream>>>(p, flag);
    };

    auto ATTN = [&](const ushort* Qhp, const ushort* Qlp, int qblocks) {
        AttnP p;
        p.Qh = Qhp; p.Ql = Qlp;
        p.Kh = kh;  p.Kl = klo;
        p.Vth = vth; p.Vtl = vtl;
        p.Op = Op; p.Ml = Ml;
        p.kvchunk = SEQ / 2; p.kvstride = SEQ;
        attn_mfma_split<<<dim3(qblocks, NH, 2), blk, 0, stream>>>(p);
    };

    // ---- stream A ----
    QKV(hs, ehs, 6, 12, true);
    vtrans_split<<<dim3(SEQ / 64, NH), blk, 0, stream>>>(v1, vth, vtl, SEQ);
    ATTN(qh, qlo, SEQ / 64);
    attn_merge<<<(SEQ * 384 + 255) / 256, blk, 0, stream>>>(Op, Ml, oA, nullptr, SEQ);

    // ---- stream C ----
    QKV(hsc, ehsc, 22, 28, false);
    rope_f32_to_split<<<(SEQ * 768 + 255) / 256, blk, 0, stream>>>(q1, pe, qh, qlo, flag, SEQ);
    rope_f32_to_split<<<(SEQ * 768 + 255) / 256, blk, 0, stream>>>(k1, pe, kh, klo, flag, SEQ);
    vtrans_split<<<dim3(SEQ / 64, NH), blk, 0, stream>>>(v1, vth, vtl, SEQ);
    rope_in_to_split<<<(IMG * 768 + 255) / 256, blk, 0, stream>>>(i2q, pe, qxh, qxl, flag, IMG);

    ATTN(qh, qlo, SEQ / 64);
    attn_merge<<<(SEQ * 384 + 255) / 256, blk, 0, stream>>>(Op, Ml, oC, nullptr, SEQ);

    // cross attention; merge folds the oA += cross add.
    ATTN(qxh, qxl, IMG / 64);
    attn_merge<<<(IMG * 384 + 255) / 256, blk, 0, stream>>>(Op, Ml, oA, oA, IMG);

    OutP op;
    op.X = oA;
    op.W[0] = W_(18); op.B[0] = W_(19);
    op.W[1] = W_(20); op.B[1] = W_(21);
    op.W[2] = W_(34); op.B[2] = W_(35);
    op.W[3] = W_(36); op.B[3] = W_(37);
    op.out = d_out;
    gemm_out_v2<<<dim3(12, 20), blk, 0, stream>>>(op, flag);
#undef W_
}

// Round 2
// 682.462 us; speedup vs baseline: 1.0519x; 1.0352x over previous
//
#include <hip/hip_runtime.h>

#define DIM 1536
#define IMG 1024
#define TXT 256
#define SEQ 1280
#define NH 24
#define HD 64
#define SD ((size_t)SEQ * DIM)
#define IDSZ ((size_t)IMG * DIM)

typedef __attribute__((ext_vector_type(8))) short short8;
typedef __attribute__((ext_vector_type(4))) float f32x4;

__device__ __forceinline__ float bf2f(ushort u) {
    union { unsigned int i; float f; } v; v.i = ((unsigned int)u) << 16; return v.f;
}
__device__ __forceinline__ ushort f2bf(float f) {
    union { unsigned int i; float f; } v; v.f = f;
    unsigned int u = v.i;
    u += 0x7fffu + ((u >> 16) & 1u);
    return (ushort)(u >> 16);
}

// ---------------------------------------------------------------------------
// Input-dtype detector (flag=1 -> fp32 underneath, flag=0 -> bf16).
// ---------------------------------------------------------------------------
__global__ __launch_bounds__(256) void detect_dtype(const void* __restrict__ p,
                                                    int* __restrict__ flag)
{
    __shared__ int cnt;
    if (threadIdx.x == 0) cnt = 0;
    __syncthreads();
    const ushort* u = (const ushort*)p;
    int local = 0;
    for (int i = threadIdx.x; i < 2048; i += 256) {
        ushort v = u[2 * i];
        int e = (v >> 7) & 0xFF;
        if (e >= 0xC0) local++;
    }
    atomicAdd(&cnt, local);
    __syncthreads();
    if (threadIdx.x == 0) flag[0] = (cnt > 16) ? 1 : 0;
}

#define LSTR 40

// ===========================================================================
// Conflict-free B plane: 128 n-rows folded into 64 LDS rows of 64 ushorts
// (row r holds n-rows r and r+64). Row stride 32 dwords == 0 mod 32 banks, so
// banks come entirely from the 3-bit granule XOR gx = g ^ (R&7) ^ (R>>3):
//  - stores (lanes step n by 8): R&7=j const, R>>3=lane -> 8 granules x 4
//    dword slots = 2 lanes/bank (free).
//  - reads (lanes step n by 1): R&7 spans l16, R>>3 spans j -> uniform
//    8 lanes/granule (aggregate-ideal for b128).
// ===========================================================================

// ===========================================================================
// Merged QKV GEMM, both streams in one launch. grid (36, 20):
//   x: wsel=x/12 in {q,k,v}; n0=(x%12)*128
//   y<10: stream A m-tiles; y>=10: stream C m-tiles. m covers img+txt rows.
// Epilogue: Y f32 (if non-null) and/or bf16 hi/lo split planes (if non-null).
// ===========================================================================
struct QKV2P {
    const void* Xi[2]; const void* Xt[2];
    const void* W[12];   // [stream*6 + wsel + (istxt?3:0)]
    const void* B[12];
    float* Y[6];         // [stream*3 + wsel]; null -> skip f32 write
    ushort* Yh[6];
    ushort* Yl[6];
};

__global__ __launch_bounds__(256) void gemm_qkv_v3(QKV2P p, const int* __restrict__ dflag)
{
    __shared__ __align__(16) ushort As[2][128 * LSTR];
    __shared__ __align__(16) ushort Bs[2][64 * 64];
    const int dt = dflag[0];
    const int bx = blockIdx.x;
    const int wsel = bx / 12;
    const int n0 = (bx - wsel * 12) * 128;
    const int ys = blockIdx.y;
    const int str = (ys >= 10) ? 1 : 0;
    const int m0g = (ys - str * 10) * 128;
    const bool istxt = (m0g >= IMG);
    const int m0 = istxt ? (m0g - IMG) : m0g;
    const void* X  = istxt ? p.Xt[str] : p.Xi[str];
    const int widx = str * 6 + wsel + (istxt ? 3 : 0);
    const void* Wp = p.W[widx];
    const void* Bp = p.B[widx];
    const int yidx = str * 3 + wsel;
    float*  Y  = p.Y[yidx];
    ushort* yh = p.Yh[yidx];
    ushort* yl = p.Yl[yidx];

    const int t = threadIdx.x;
    const int wave = t >> 6, lane = t & 63;
    const int quad = lane >> 4, l16 = lane & 15;
    const int wm = (wave >> 1) * 64, wn = (wave & 1) * 64;

    const int arow = t >> 1, apair = t & 1;
    const int bn8 = (t & 15) << 3, bkk = (t >> 4) << 1;
    const int aps = apair ^ ((arow >> 3) & 1);
    const int adst = arow * LSTR + aps * 16;
    const int bkg = bkk >> 3, bo = bkk & 7;

    f32x4 acc[4][4];
#pragma unroll
    for (int i = 0; i < 4; ++i)
#pragma unroll
        for (int j = 0; j < 4; ++j) acc[i][j] = (f32x4)(0.0f);

    float4 raf[4]; uint4 rau[2];
    float4 rbf[4]; uint4 rbu[2];

    auto loadA = [&](int k0) {
        const size_t off = (size_t)(m0 + arow) * DIM + k0 + apair * 16;
        if (dt) {
            const float* xp = (const float*)X + off;
            raf[0] = *(const float4*)xp;       raf[1] = *(const float4*)(xp + 4);
            raf[2] = *(const float4*)(xp + 8); raf[3] = *(const float4*)(xp + 12);
        } else {
            const ushort* xp = (const ushort*)X + off;
            rau[0] = *(const uint4*)xp;
            rau[1] = *(const uint4*)(xp + 8);
        }
    };
    auto loadB = [&](int k0) {
        const size_t off = (size_t)(k0 + bkk) * DIM + n0 + bn8;
        if (dt) {
            const float* wp0 = (const float*)Wp + off;
            rbf[0] = *(const float4*)wp0;         rbf[1] = *(const float4*)(wp0 + 4);
            rbf[2] = *(const float4*)(wp0 + DIM); rbf[3] = *(const float4*)(wp0 + DIM + 4);
        } else {
            const ushort* wp0 = (const ushort*)Wp + off;
            rbu[0] = *(const uint4*)wp0;
            rbu[1] = *(const uint4*)(wp0 + DIM);
        }
    };
    auto storeA = [&](int buf) {
        ushort tmp[16];
        if (dt) {
            const float* xs = (const float*)raf;
#pragma unroll
            for (int i = 0; i < 16; ++i) tmp[i] = f2bf(xs[i]);
        } else {
            *(uint4*)&tmp[0] = rau[0];
            *(uint4*)&tmp[8] = rau[1];
        }
        *(uint4*)&As[buf][adst]     = *(uint4*)&tmp[0];
        *(uint4*)&As[buf][adst + 8] = *(uint4*)&tmp[8];
    };
    auto storeB = [&](int buf) {
        ushort t0[8], t1[8];
        if (dt) {
            const float* f = (const float*)rbf;
#pragma unroll
            for (int j = 0; j < 8; ++j) { t0[j] = f2bf(f[j]); t1[j] = f2bf(f[8 + j]); }
        } else {
            *(uint4*)t0 = rbu[0];
            *(uint4*)t1 = rbu[1];
        }
#pragma unroll
        for (int j = 0; j < 8; ++j) {
            const int rr = bn8 + j;
            const int R = rr & 63, half = rr >> 6;
            const int gx = (((half << 2) + bkg) ^ (R & 7) ^ (R >> 3)) & 7;
            *(unsigned int*)&Bs[buf][R * 64 + gx * 8 + bo] =
                (unsigned int)t0[j] | ((unsigned int)t1[j] << 16);
        }
    };

    loadA(0); loadB(0);
    storeA(0); storeB(0);
    __syncthreads();

    for (int k = 0; k < DIM / 32; ++k) {
        const int cur = k & 1;
        const bool hn = (k + 1) < DIM / 32;
        if (hn) { loadA((k + 1) * 32); loadB((k + 1) * 32); }

        short8 b[4];
#pragma unroll
        for (int j = 0; j < 4; ++j) {
            const int rrn = wn + j * 16 + l16;
            const int R = rrn & 63, half = rrn >> 6;
            const int gx = (((half << 2) + quad) ^ (R & 7) ^ (R >> 3)) & 7;
            b[j] = *(const short8*)&Bs[cur][R * 64 + gx * 8];
        }
#pragma unroll
        for (int i = 0; i < 4; ++i) {
            const int rr = wm + i * 16 + l16;
            const int ps = (quad >> 1) ^ ((rr >> 3) & 1);
            const int col = ps * 16 + (quad & 1) * 8;
            short8 a = *(const short8*)&As[cur][rr * LSTR + col];
#pragma unroll
            for (int j = 0; j < 4; ++j)
                acc[i][j] = __builtin_amdgcn_mfma_f32_16x16x32_bf16(a, b[j], acc[i][j], 0, 0, 0);
        }
        if (hn) { storeA(cur ^ 1); storeB(cur ^ 1); }
        __syncthreads();
    }

#pragma unroll
    for (int j = 0; j < 4; ++j) {
        const int col = n0 + wn + j * 16 + l16;
        const float bv = dt ? ((const float*)Bp)[col] : bf2f(((const ushort*)Bp)[col]);
#pragma unroll
        for (int i = 0; i < 4; ++i)
#pragma unroll
            for (int r = 0; r < 4; ++r) {
                const int row = m0g + wm + i * 16 + quad * 4 + r;
                const size_t o = (size_t)row * DIM + col;
                const float val = acc[i][j][r] + bv;
                if (Y) Y[o] = val;
                if (yh) {
                    const ushort hv = f2bf(val);
                    yh[o] = hv;
                    yl[o] = f2bf(val - bf2f(hv));
                }
            }
    }
}

// ===========================================================================
// Merged output projections, 64-row m-tiles for occupancy. grid (12, 40).
// X = 2560 contiguous f32 rows (oA 1280 + oC 1280), hi/lo split A.
// Segments: mt<16 a_out, <20 a_addout, <36 c_out, else c_addout.
// ===========================================================================
struct OutP {
    const float* X;
    const void* W[4]; const void* B[4];
    void* out;
};

__global__ __launch_bounds__(256) void gemm_out_v3(OutP p, const int* __restrict__ dflag)
{
    __shared__ __align__(16) ushort Ah[2][64 * LSTR];
    __shared__ __align__(16) ushort Al[2][64 * LSTR];
    __shared__ __align__(16) ushort Bs[2][64 * 64];
    const int dt = dflag[0];
    const int n0 = blockIdx.x * 128;
    const int mt = blockIdx.y;
    const int seg = (mt < 16) ? 0 : (mt < 20) ? 1 : (mt < 36) ? 2 : 3;
    const void* Wp = p.W[seg];
    const void* Bp = p.B[seg];
    const int m0 = mt * 64;

    const int t = threadIdx.x;
    const int wave = t >> 6, lane = t & 63;
    const int quad = lane >> 4, l16 = lane & 15;
    const int wm = (wave >> 1) * 32, wn = (wave & 1) * 64;

    const int arow = t >> 2, ag = t & 3;
    const int apg = ag >> 1, asub = ag & 1;
    const int aps = apg ^ ((arow >> 3) & 1);
    const int adst = arow * LSTR + aps * 16 + asub * 8;
    const int bn8 = (t & 15) << 3, bkk = (t >> 4) << 1;
    const int bkg = bkk >> 3, bo = bkk & 7;

    f32x4 acc[2][4];
#pragma unroll
    for (int i = 0; i < 2; ++i)
#pragma unroll
        for (int j = 0; j < 4; ++j) acc[i][j] = (f32x4)(0.0f);

    float4 raf[2];
    float4 rbf[4]; uint4 rbu[2];

    auto loadA = [&](int k0) {
        const float* xp = p.X + (size_t)(m0 + arow) * DIM + k0 + ag * 8;
        raf[0] = *(const float4*)xp;
        raf[1] = *(const float4*)(xp + 4);
    };
    auto loadB = [&](int k0) {
        const size_t off = (size_t)(k0 + bkk) * DIM + n0 + bn8;
        if (dt) {
            const float* wp0 = (const float*)Wp + off;
            rbf[0] = *(const float4*)wp0;         rbf[1] = *(const float4*)(wp0 + 4);
            rbf[2] = *(const float4*)(wp0 + DIM); rbf[3] = *(const float4*)(wp0 + DIM + 4);
        } else {
            const ushort* wp0 = (const ushort*)Wp + off;
            rbu[0] = *(const uint4*)wp0;
            rbu[1] = *(const uint4*)(wp0 + DIM);
        }
    };
    auto storeA = [&](int buf) {
        ushort hi[8], lo[8];
        const float* xs = (const float*)raf;
#pragma unroll
        for (int i = 0; i < 8; ++i) {
            hi[i] = f2bf(xs[i]);
            lo[i] = f2bf(xs[i] - bf2f(hi[i]));
        }
        *(uint4*)&Ah[buf][adst] = *(uint4*)&hi[0];
        *(uint4*)&Al[buf][adst] = *(uint4*)&lo[0];
    };
    auto storeB = [&](int buf) {
        ushort t0[8], t1[8];
        if (dt) {
            const float* f = (const float*)rbf;
#pragma unroll
            for (int j = 0; j < 8; ++j) { t0[j] = f2bf(f[j]); t1[j] = f2bf(f[8 + j]); }
        } else {
            *(uint4*)t0 = rbu[0];
            *(uint4*)t1 = rbu[1];
        }
#pragma unroll
        for (int j = 0; j < 8; ++j) {
            const int rr = bn8 + j;
            const int R = rr & 63, half = rr >> 6;
            const int gx = (((half << 2) + bkg) ^ (R & 7) ^ (R >> 3)) & 7;
            *(unsigned int*)&Bs[buf][R * 64 + gx * 8 + bo] =
                (unsigned int)t0[j] | ((unsigned int)t1[j] << 16);
        }
    };

    loadA(0); loadB(0);
    storeA(0); storeB(0);
    __syncthreads();

    for (int k = 0; k < DIM / 32; ++k) {
        const int cur = k & 1;
        const bool hn = (k + 1) < DIM / 32;
        if (hn) { loadA((k + 1) * 32); loadB((k + 1) * 32); }

        short8 b[4];
#pragma unroll
        for (int j = 0; j < 4; ++j) {
            const int rrn = wn + j * 16 + l16;
            const int R = rrn & 63, half = rrn >> 6;
            const int gx = (((half << 2) + quad) ^ (R & 7) ^ (R >> 3)) & 7;
            b[j] = *(const short8*)&Bs[cur][R * 64 + gx * 8];
        }
#pragma unroll
        for (int i = 0; i < 2; ++i) {
            const int rr = wm + i * 16 + l16;
            const int ps = (quad >> 1) ^ ((rr >> 3) & 1);
            const int col = ps * 16 + (quad & 1) * 8;
            short8 ah = *(const short8*)&Ah[cur][rr * LSTR + col];
            short8 al = *(const short8*)&Al[cur][rr * LSTR + col];
#pragma unroll
            for (int j = 0; j < 4; ++j) {
                acc[i][j] = __builtin_amdgcn_mfma_f32_16x16x32_bf16(ah, b[j], acc[i][j], 0, 0, 0);
                acc[i][j] = __builtin_amdgcn_mfma_f32_16x16x32_bf16(al, b[j], acc[i][j], 0, 0, 0);
            }
        }
        if (hn) { storeA(cur ^ 1); storeB(cur ^ 1); }
        __syncthreads();
    }

#pragma unroll
    for (int j = 0; j < 4; ++j) {
        const int col = n0 + wn + j * 16 + l16;
        const float bv = dt ? ((const float*)Bp)[col] : bf2f(((const ushort*)Bp)[col]);
#pragma unroll
        for (int i = 0; i < 2; ++i)
#pragma unroll
            for (int r = 0; r < 4; ++r) {
                const int grow = m0 + wm + i * 16 + quad * 4 + r;
                const size_t o = (size_t)grow * DIM + col;
                const float val = acc[i][j][r] + bv;
                if (dt) ((float*)p.out)[o] = val;
                else    ((ushort*)p.out)[o] = f2bf(val);
            }
    }
}

// ---------------------------------------------------------------------------
// RoPE kernels -> bf16 hi/lo split planes. pe: s*128 + i*4 + {c,-s,s,c}.
// ---------------------------------------------------------------------------
__device__ __forceinline__ void pe_load(const void* pe, int dt, size_t off,
                                        float& c00, float& c01, float& c10, float& c11)
{
    if (dt) {
        float4 pv = *(const float4*)((const float*)pe + off);
        c00 = pv.x; c01 = pv.y; c10 = pv.z; c11 = pv.w;
    } else {
        const ushort* pp = (const ushort*)pe + off;
        c00 = bf2f(pp[0]); c01 = bf2f(pp[1]); c10 = bf2f(pp[2]); c11 = bf2f(pp[3]);
    }
}

__global__ __launch_bounds__(256) void rope_f32_to_split(
    const float* __restrict__ src, const void* __restrict__ pe,
    ushort* __restrict__ dh, ushort* __restrict__ dl,
    const int* __restrict__ dflag, int S)
{
    const int dt = dflag[0];
    int idx = blockIdx.x * 256 + threadIdx.x;
    if (idx >= S * 768) return;
    int s = idx / 768, pp = idx - s * 768;
    int col = pp << 1, i = pp & 31;
    float2 xv = *(const float2*)(src + (size_t)s * DIM + col);
    float c00, c01, c10, c11;
    pe_load(pe, dt, (size_t)s * 128 + i * 4, c00, c01, c10, c11);
    float y0 = c00 * xv.x + c01 * xv.y;
    float y1 = c10 * xv.x + c11 * xv.y;
    ushort h0 = f2bf(y0), h1 = f2bf(y1);
    ushort l0 = f2bf(y0 - bf2f(h0)), l1 = f2bf(y1 - bf2f(h1));
    *(unsigned int*)(dh + (size_t)s * DIM + col) = (unsigned int)h0 | ((unsigned int)h1 << 16);
    *(unsigned int*)(dl + (size_t)s * DIM + col) = (unsigned int)l0 | ((unsigned int)l1 << 16);
}

__global__ __launch_bounds__(256) void rope_in_to_split(
    const void* __restrict__ src, const void* __restrict__ pe,
    ushort* __restrict__ dh, ushort* __restrict__ dl,
    const int* __restrict__ dflag, int S)
{
    const int dt = dflag[0];
    int idx = blockIdx.x * 256 + threadIdx.x;
    if (idx >= S * 768) return;
    int s = idx / 768, pp = idx - s * 768;
    int col = pp << 1, i = pp & 31;
    float x0, x1;
    if (dt) {
        float2 xv = *(const float2*)((const float*)src + (size_t)s * DIM + col);
        x0 = xv.x; x1 = xv.y;
    } else {
        const ushort* sp = (const ushort*)src + (size_t)s * DIM + col;
        x0 = bf2f(sp[0]); x1 = bf2f(sp[1]);
    }
    float c00, c01, c10, c11;
    pe_load(pe, dt, (size_t)s * 128 + i * 4, c00, c01, c10, c11);
    float y0 = c00 * x0 + c01 * x1;
    float y1 = c10 * x0 + c11 * x1;
    ushort h0 = f2bf(y0), h1 = f2bf(y1);
    ushort l0 = f2bf(y0 - bf2f(h0)), l1 = f2bf(y1 - bf2f(h1));
    *(unsigned int*)(dh + (size_t)s * DIM + col) = (unsigned int)h0 | ((unsigned int)h1 << 16);
    *(unsigned int*)(dl + (size_t)s * DIM + col) = (unsigned int)l0 | ((unsigned int)l1 << 16);
}

// ---------------------------------------------------------------------------
// V transpose+split: f32 [seq][DIM] -> hi/lo bf16 [h*64+d][seq].
// ---------------------------------------------------------------------------
__global__ __launch_bounds__(256) void vtrans_split(
    const float* __restrict__ V, ushort* __restrict__ Vth, ushort* __restrict__ Vtl,
    int seq)
{
    __shared__ unsigned int tile[64 * 65];
    const int s0 = blockIdx.x * 64;
    const int h = blockIdx.y;
    const int t = threadIdx.x;
#pragma unroll
    for (int it = 0; it < 16; ++it) {
        const int sl = (t >> 6) + (it << 2);
        const int d = t & 63;
        const float v = V[(size_t)(s0 + sl) * DIM + h * HD + d];
        const ushort hv = f2bf(v);
        const ushort lv = f2bf(v - bf2f(hv));
        tile[d * 65 + sl] = (unsigned int)hv | ((unsigned int)lv << 16);
    }
    __syncthreads();
    const int d = t >> 2, cc = (t & 3) << 4;
    ushort th[16], tl[16];
#pragma unroll
    for (int j = 0; j < 16; ++j) {
        const unsigned int w = tile[d * 65 + cc + j];
        th[j] = (ushort)w;
        tl[j] = (ushort)(w >> 16);
    }
    const size_t off = (size_t)(h * HD + d) * seq + s0 + cc;
    *(uint4*)(Vth + off)     = *(uint4*)&th[0];
    *(uint4*)(Vth + off + 8) = *(uint4*)&th[8];
    *(uint4*)(Vtl + off)     = *(uint4*)&tl[0];
    *(uint4*)(Vtl + off + 8) = *(uint4*)&tl[8];
}

// ---------------------------------------------------------------------------
// MFMA flash attention, KV-split (grid.z = 2) over pre-split bf16 hi/lo
// operands. Writes unnormalized O partials + (m,l); merge kernel combines.
// ---------------------------------------------------------------------------
__device__ __forceinline__ int swz(int row, int col) {
    return row * 64 + ((((col >> 3) ^ row) & 7) << 3) + (col & 7);
}
__device__ __forceinline__ short8 ldfrag(const ushort* plane, int row, int col) {
    return *(const short8*)&plane[swz(row, col)];
}

struct AttnP {
    const ushort *Qh, *Ql, *Kh, *Kl, *Vth, *Vtl;
    float* Op0;     // z=0 partial plane (aliases a dead f32 buffer)
    float* Op1;     // z=1 partial plane
    float2* Ml;     // [2][NH][SEQ] (m,l)
    int kvchunk;    // kv positions per z-split (640)
    int kvstride;   // seq stride of Vt layout (SEQ)
};

__global__ __launch_bounds__(256) void attn_mfma_split(AttnP p)
{
    __shared__ ushort Qh_[4096], Ql_[4096];
    __shared__ ushort Kh_[4096], Kl_[4096];
    __shared__ ushort Vh_[4096], Vl_[4096];

    const int q0 = blockIdx.x * 64;
    const int h = blockIdx.y;
    const int z = blockIdx.z;
    const int t = threadIdx.x;
    const int wave = t >> 6, lane = t & 63;
    const int quad = lane >> 4, l16 = lane & 15;
    const int wq0 = wave * 16;

    const int srow = t >> 2, c0 = (t & 3) << 4;
    const int g0 = c0 >> 3;
    const int p0 = ((g0 ^ (srow & 7)) & 7) << 3;
    const int p1 = (((g0 + 1) ^ (srow & 7)) & 7) << 3;

    {
        const size_t off = (size_t)(q0 + srow) * DIM + h * HD + c0;
        *(uint4*)&Qh_[srow * 64 + p0] = *(const uint4*)(p.Qh + off);
        *(uint4*)&Qh_[srow * 64 + p1] = *(const uint4*)(p.Qh + off + 8);
        *(uint4*)&Ql_[srow * 64 + p0] = *(const uint4*)(p.Ql + off);
        *(uint4*)&Ql_[srow * 64 + p1] = *(const uint4*)(p.Ql + off + 8);
    }
    short8 qfh[2], qfl[2];
#pragma unroll
    for (int c = 0; c < 2; ++c) {
        qfh[c] = ldfrag(Qh_, wq0 + l16, c * 32 + quad * 8);
        qfl[c] = ldfrag(Ql_, wq0 + l16, c * 32 + quad * 8);
    }

    float m_[4], l_[4];
#pragma unroll
    for (int r = 0; r < 4; ++r) { m_[r] = -3e38f; l_[r] = 0.0f; }
    f32x4 Oacc[4];
#pragma unroll
    for (int j = 0; j < 4; ++j) Oacc[j] = (f32x4)(0.0f);

    const int kvbeg = z * p.kvchunk;
    for (int kt = 0; kt < p.kvchunk; kt += 64) {
        const int kv0 = kvbeg + kt;
        __syncthreads();
        {
            const size_t off = (size_t)(kv0 + srow) * DIM + h * HD + c0;
            *(uint4*)&Kh_[srow * 64 + p0] = *(const uint4*)(p.Kh + off);
            *(uint4*)&Kh_[srow * 64 + p1] = *(const uint4*)(p.Kh + off + 8);
            *(uint4*)&Kl_[srow * 64 + p0] = *(const uint4*)(p.Kl + off);
            *(uint4*)&Kl_[srow * 64 + p1] = *(const uint4*)(p.Kl + off + 8);
        }
        {
            const size_t off = (size_t)(h * HD + srow) * p.kvstride + kv0 + c0;
            *(uint4*)&Vh_[srow * 64 + p0] = *(const uint4*)(p.Vth + off);
            *(uint4*)&Vh_[srow * 64 + p1] = *(const uint4*)(p.Vth + off + 8);
            *(uint4*)&Vl_[srow * 64 + p0] = *(const uint4*)(p.Vtl + off);
            *(uint4*)&Vl_[srow * 64 + p1] = *(const uint4*)(p.Vtl + off + 8);
        }
        __syncthreads();

        f32x4 S[4];
#pragma unroll
        for (int j = 0; j < 4; ++j) S[j] = (f32x4)(0.0f);
#pragma unroll
        for (int c = 0; c < 2; ++c) {
#pragma unroll
            for (int j = 0; j < 4; ++j) {
                short8 bh = ldfrag(Kh_, j * 16 + l16, c * 32 + quad * 8);
                short8 bl = ldfrag(Kl_, j * 16 + l16, c * 32 + quad * 8);
                S[j] = __builtin_amdgcn_mfma_f32_16x16x32_bf16(qfh[c], bh, S[j], 0, 0, 0);
                S[j] = __builtin_amdgcn_mfma_f32_16x16x32_bf16(qfl[c], bh, S[j], 0, 0, 0);
                S[j] = __builtin_amdgcn_mfma_f32_16x16x32_bf16(qfh[c], bl, S[j], 0, 0, 0);
            }
        }
#pragma unroll
        for (int j = 0; j < 4; ++j)
#pragma unroll
            for (int r = 0; r < 4; ++r) S[j][r] *= 0.125f;

        float alpha[4];
#pragma unroll
        for (int r = 0; r < 4; ++r) {
            float mx = fmaxf(fmaxf(S[0][r], S[1][r]), fmaxf(S[2][r], S[3][r]));
            mx = fmaxf(mx, __shfl_xor(mx, 1));
            mx = fmaxf(mx, __shfl_xor(mx, 2));
            mx = fmaxf(mx, __shfl_xor(mx, 4));
            mx = fmaxf(mx, __shfl_xor(mx, 8));
            float mn = fmaxf(m_[r], mx);
            alpha[r] = __expf(m_[r] - mn);
            m_[r] = mn;
            float rs = 0.0f;
#pragma unroll
            for (int j = 0; j < 4; ++j) {
                float pv = __expf(S[j][r] - mn);
                S[j][r] = pv;
                rs += pv;
            }
            rs += __shfl_xor(rs, 1);
            rs += __shfl_xor(rs, 2);
            rs += __shfl_xor(rs, 4);
            rs += __shfl_xor(rs, 8);
            l_[r] = l_[r] * alpha[r] + rs;
        }
#pragma unroll
        for (int j = 0; j < 4; ++j)
#pragma unroll
            for (int r = 0; r < 4; ++r) Oacc[j][r] *= alpha[r];

        {
            const int prow = wq0 + quad * 4;
#pragma unroll
            for (int j = 0; j < 4; ++j)
#pragma unroll
                for (int r = 0; r < 4; ++r) {
                    float pv = S[j][r];
                    ushort ph = f2bf(pv);
                    ushort pl = f2bf(pv - bf2f(ph));
                    int idx = swz(prow + r, j * 16 + l16);
                    Qh_[idx] = ph;
                    Ql_[idx] = pl;
                }
        }

#pragma unroll
        for (int c = 0; c < 2; ++c) {
            short8 pah = ldfrag(Qh_, wq0 + l16, c * 32 + quad * 8);
            short8 pal = ldfrag(Ql_, wq0 + l16, c * 32 + quad * 8);
#pragma unroll
            for (int jn = 0; jn < 4; ++jn) {
                short8 vbh = ldfrag(Vh_, jn * 16 + l16, c * 32 + quad * 8);
                short8 vbl = ldfrag(Vl_, jn * 16 + l16, c * 32 + quad * 8);
                Oacc[jn] = __builtin_amdgcn_mfma_f32_16x16x32_bf16(pah, vbh, Oacc[jn], 0, 0, 0);
                Oacc[jn] = __builtin_amdgcn_mfma_f32_16x16x32_bf16(pal, vbh, Oacc[jn], 0, 0, 0);
                Oacc[jn] = __builtin_amdgcn_mfma_f32_16x16x32_bf16(pah, vbl, Oacc[jn], 0, 0, 0);
            }
        }
    }

    float* Opz = z ? p.Op1 : p.Op0;
#pragma unroll
    for (int r = 0; r < 4; ++r) {
        const int rowq = q0 + wq0 + quad * 4 + r;
        if (l16 == 0)
            p.Ml[((size_t)z * NH + h) * SEQ + rowq] = make_float2(m_[r], l_[r]);
#pragma unroll
        for (int jn = 0; jn < 4; ++jn)
            Opz[(size_t)rowq * DIM + h * HD + jn * 16 + l16] = Oacc[jn][r];
    }
}

// Merge NSPLIT=2 partials: O = sum_z e^{m_z-m*} O_z / sum_z e^{m_z-m*} l_z.
// Elementwise-safe even when out aliases Op1. Optional addto fold.
__global__ __launch_bounds__(256) void attn_merge(
    const float* __restrict__ Op0, const float* __restrict__ Op1,
    const float2* __restrict__ Ml,
    float* __restrict__ out, const float* __restrict__ addto, int qlen)
{
    const int idx = blockIdx.x * 256 + threadIdx.x;
    if (idx >= qlen * 384) return;
    const int rowq = idx / 384;
    const int c4 = (idx - rowq * 384) << 2;
    const float2 a = Ml[(size_t)(c4 >> 6) * SEQ + rowq];
    const float2 b = Ml[(size_t)(NH + (c4 >> 6)) * SEQ + rowq];
    const float ms = fmaxf(a.x, b.x);
    const float s0 = __expf(a.x - ms), s1 = __expf(b.x - ms);
    const float inv = 1.0f / (s0 * a.y + s1 * b.y);
    const float4 o0 = *(const float4*)&Op0[(size_t)rowq * DIM + c4];
    const float4 o1 = *(const float4*)&Op1[(size_t)rowq * DIM + c4];
    float4 r;
    r.x = (s0 * o0.x + s1 * o1.x) * inv;
    r.y = (s0 * o0.y + s1 * o1.y) * inv;
    r.z = (s0 * o0.z + s1 * o1.z) * inv;
    r.w = (s0 * o0.w + s1 * o1.w) * inv;
    if (addto) {
        const float4 c = *(const float4*)&addto[(size_t)rowq * DIM + c4];
        r.x += c.x; r.y += c.y; r.z += c.z; r.w += c.w;
    }
    *(float4*)&out[(size_t)rowq * DIM + c4] = r;
}

// ---------------------------------------------------------------------------
extern "C" void kernel_launch(void* const* d_in, const int* in_sizes, int n_in,
                              void* d_out, int out_size, void* d_ws, size_t ws_size,
                              hipStream_t stream) {
    (void)in_sizes; (void)n_in; (void)out_size; (void)ws_size;
    const void* hs   = d_in[0];
    const void* ehs  = d_in[1];
    const void* hsc  = d_in[2];
    const void* ehsc = d_in[3];
    const void* i2q  = d_in[4];
    const void* pe   = d_in[5];
#define W_(i) ((const void*)d_in[i])

    int*   flag = (int*)d_ws;
    float* fb = (float*)((char*)d_ws + 256);
    float* q1 = fb;            // C's q f32
    float* k1 = q1 + SD;       // C's k f32
    float* v1 = k1 + SD;       // A's v f32; later attn partial plane 0
    float* vC = v1 + SD;       // C's v f32; later attnX partial plane 1
    float* oA = vC + SD;       // SD f32 (out-proj X rows 0..1279)
    float* oC = oA + SD;       // SD f32 (MUST be oA+SD); partial plane 1 for A/C attns
    ushort* qh  = (ushort*)(oC + SD);  // split planes, SD ushorts each
    ushort* qlo = qh + SD;
    ushort* kh  = qlo + SD;
    ushort* klo = kh + SD;
    ushort* vth = klo + SD;
    ushort* vtl = vth + SD;
    ushort* qxh = vtl + SD;    // IDSZ ushorts
    ushort* qxl = qxh + IDSZ;
    float2* Ml = (float2*)(qxl + IDSZ);  // 2*NH*SEQ float2

    dim3 blk(256);
    detect_dtype<<<1, blk, 0, stream>>>(hs, flag);

    // ---- merged QKV for both streams ----
    QKV2P qp;
    qp.Xi[0] = hs;  qp.Xt[0] = ehs;
    qp.Xi[1] = hsc; qp.Xt[1] = ehsc;
    for (int j = 0; j < 3; ++j) {
        qp.W[j]     = W_(6 + 2 * j);   qp.B[j]     = W_(7 + 2 * j);
        qp.W[3 + j] = W_(12 + 2 * j);  qp.B[3 + j] = W_(13 + 2 * j);
        qp.W[6 + j] = W_(22 + 2 * j);  qp.B[6 + j] = W_(23 + 2 * j);
        qp.W[9 + j] = W_(28 + 2 * j);  qp.B[9 + j] = W_(29 + 2 * j);
    }
    for (int j = 0; j < 6; ++j) { qp.Y[j] = nullptr; qp.Yh[j] = nullptr; qp.Yl[j] = nullptr; }
    qp.Yh[0] = qh;  qp.Yl[0] = qlo;   // A q: splits only
    qp.Yh[1] = kh;  qp.Yl[1] = klo;   // A k: splits only
    qp.Y[2] = v1;                     // A v: f32 for vtrans
    qp.Y[3] = q1;                     // C q: f32 for rope
    qp.Y[4] = k1;                     // C k: f32 for rope
    qp.Y[5] = vC;                     // C v: f32 for vtrans
    gemm_qkv_v3<<<dim3(36, 20), blk, 0, stream>>>(qp, flag);

    auto ATTN = [&](const ushort* Qhp, const ushort* Qlp, int qblocks,
                    float* Op0, float* Op1) {
        AttnP p;
        p.Qh = Qhp; p.Ql = Qlp;
        p.Kh = kh;  p.Kl = klo;
        p.Vth = vth; p.Vtl = vtl;
        p.Op0 = Op0; p.Op1 = Op1; p.Ml = Ml;
        p.kvchunk = SEQ / 2; p.kvstride = SEQ;
        attn_mfma_split<<<dim3(qblocks, NH, 2), blk, 0, stream>>>(p);
    };

    // ---- stream A attention ----
    vtrans_split<<<dim3(SEQ / 64, NH), blk, 0, stream>>>(v1, vth, vtl, SEQ);
    ATTN(qh, qlo, SEQ / 64, v1, oC);                 // v1 dead post-vtrans; oC not yet live
    attn_merge<<<(SEQ * 384 + 255) / 256, blk, 0, stream>>>(v1, oC, Ml, oA, nullptr, SEQ);

    // ---- stream C prep (reuses A's split-plane buffers; A attn is done) ----
    rope_f32_to_split<<<(SEQ * 768 + 255) / 256, blk, 0, stream>>>(q1, pe, qh, qlo, flag, SEQ);
    rope_f32_to_split<<<(SEQ * 768 + 255) / 256, blk, 0, stream>>>(k1, pe, kh, klo, flag, SEQ);
    rope_in_to_split<<<(IMG * 768 + 255) / 256, blk, 0, stream>>>(i2q, pe, qxh, qxl, flag, IMG);
    vtrans_split<<<dim3(SEQ / 64, NH), blk, 0, stream>>>(vC, vth, vtl, SEQ);

    // ---- stream C self attention ----
    ATTN(qh, qlo, SEQ / 64, v1, oC);
    attn_merge<<<(SEQ * 384 + 255) / 256, blk, 0, stream>>>(v1, oC, Ml, oC, nullptr, SEQ);

    // ---- cross attention; merge folds oA += cross ----
    ATTN(qxh, qxl, IMG / 64, v1, vC);                // vC dead post-vtrans
    attn_merge<<<(IMG * 384 + 255) / 256, blk, 0, stream>>>(v1, vC, Ml, oA, oA, IMG);

    OutP op;
    op.X = oA;
    op.W[0] = W_(18); op.B[0] = W_(19);
    op.W[1] = W_(20); op.B[1] = W_(21);
    op.W[2] = W_(34); op.B[2] = W_(35);
    op.W[3] = W_(36); op.B[3] = W_(37);
    op.out = d_out;
    gemm_out_v3<<<dim3(12, 40), blk, 0, stream>>>(op, flag);
#undef W_
}

// Round 3
// 654.880 us; speedup vs baseline: 1.0962x; 1.0421x over previous
//
#include <hip/hip_runtime.h>

#define DIM 1536
#define IMG 1024
#define TXT 256
#define SEQ 1280
#define NH 24
#define HD 64
#define SD ((size_t)SEQ * DIM)
#define IDSZ ((size_t)IMG * DIM)
#define WSZ ((size_t)DIM * DIM)

typedef __attribute__((ext_vector_type(8))) short short8;
typedef __attribute__((ext_vector_type(4))) float f32x4;

__device__ __forceinline__ float bf2f(ushort u) {
    union { unsigned int i; float f; } v; v.i = ((unsigned int)u) << 16; return v.f;
}
__device__ __forceinline__ ushort f2bf(float f) {
    union { unsigned int i; float f; } v; v.f = f;
    unsigned int u = v.i;
    u += 0x7fffu + ((u >> 16) & 1u);
    return (ushort)(u >> 16);
}

// ---------------------------------------------------------------------------
// Input-dtype detector (flag=1 -> fp32 underneath, flag=0 -> bf16).
// ---------------------------------------------------------------------------
__global__ __launch_bounds__(256) void detect_dtype(const void* __restrict__ p,
                                                    int* __restrict__ flag)
{
    __shared__ int cnt;
    if (threadIdx.x == 0) cnt = 0;
    __syncthreads();
    const ushort* u = (const ushort*)p;
    int local = 0;
    for (int i = threadIdx.x; i < 2048; i += 256) {
        ushort v = u[2 * i];
        int e = (v >> 7) & 0xFF;
        if (e >= 0xC0) local++;
    }
    atomicAdd(&cnt, local);
    __syncthreads();
    if (threadIdx.x == 0) flag[0] = (cnt > 16) ? 1 : 0;
}

// ---------------------------------------------------------------------------
// One-time bf16 conversion of QKV weights + X inputs (copy when already bf16).
// ---------------------------------------------------------------------------
struct CvtP {
    const void* src[16];
    ushort* dst[16];
    int n8[16];
};

__global__ __launch_bounds__(256) void convert_bf16(CvtP p, const int* __restrict__ dflag)
{
    const int a = blockIdx.y;
    const int i = blockIdx.x * 256 + threadIdx.x;
    if (i >= p.n8[a]) return;
    const size_t off = (size_t)i * 8;
    uint4 o;
    if (dflag[0]) {
        const float* s = (const float*)p.src[a] + off;
        const float4 f0 = *(const float4*)s;
        const float4 f1 = *(const float4*)(s + 4);
        ushort t[8];
        t[0] = f2bf(f0.x); t[1] = f2bf(f0.y); t[2] = f2bf(f0.z); t[3] = f2bf(f0.w);
        t[4] = f2bf(f1.x); t[5] = f2bf(f1.y); t[6] = f2bf(f1.z); t[7] = f2bf(f1.w);
        o = *(uint4*)t;
    } else {
        o = *(const uint4*)((const ushort*)p.src[a] + off);
    }
    *(uint4*)(p.dst[a] + off) = o;
}

#define LSTR 40

// ===========================================================================
// Merged QKV GEMM over pre-converted bf16 X and W. grid (36, 20):
//   x: wsel=x/12 in {q,k,v}; n0=(x%12)*128
//   y<10: stream A m-tiles; y>=10: stream C. m covers merged img+txt rows.
// Staging is pure uint4 moves (no conversion). Epilogue: optional f32 Y
// and/or bf16 hi/lo split planes.
// B plane: 128 n-rows folded into 64 LDS rows of 64 ushorts, 3-bit granule
// XOR gx = ((half<<2)+g) ^ (R&7) ^ (R>>3): stores 2 lanes/bank (free),
// reads uniform 8 lanes/granule.
// ===========================================================================
struct QKV3P {
    const ushort* Xb;    // [2][SEQ][DIM] bf16 (img rows then txt rows)
    const ushort* Wb;    // [12][DIM][DIM] bf16, idx = str*6 + wsel + istxt*3
    const void* B[12];   // bias (original dtype)
    float* Y[6];         // [str*3 + wsel]; null -> skip f32 write
    ushort* Yh[6];
    ushort* Yl[6];
};

__global__ __launch_bounds__(256) void gemm_qkv_v4(QKV3P p, const int* __restrict__ dflag)
{
    __shared__ __align__(16) ushort As[2][128 * LSTR];
    __shared__ __align__(16) ushort Bs[2][64 * 64];
    const int dt = dflag[0];
    const int bx = blockIdx.x;
    const int wsel = bx / 12;
    const int n0 = (bx - wsel * 12) * 128;
    const int ys = blockIdx.y;
    const int str = (ys >= 10) ? 1 : 0;
    const int m0g = (ys - str * 10) * 128;
    const bool istxt = (m0g >= IMG);
    const int widx = str * 6 + wsel + (istxt ? 3 : 0);
    const ushort* X  = p.Xb + (size_t)str * SD;
    const ushort* Wp = p.Wb + (size_t)widx * WSZ;
    const void* Bp = p.B[widx];
    const int yidx = str * 3 + wsel;
    float*  Y  = p.Y[yidx];
    ushort* yh = p.Yh[yidx];
    ushort* yl = p.Yl[yidx];

    const int t = threadIdx.x;
    const int wave = t >> 6, lane = t & 63;
    const int quad = lane >> 4, l16 = lane & 15;
    const int wm = (wave >> 1) * 64, wn = (wave & 1) * 64;

    const int arow = t >> 1, apair = t & 1;
    const int bn8 = (t & 15) << 3, bkk = (t >> 4) << 1;
    const int aps = apair ^ ((arow >> 3) & 1);
    const int adst = arow * LSTR + aps * 16;
    const int bkg = bkk >> 3, bo = bkk & 7;

    f32x4 acc[4][4];
#pragma unroll
    for (int i = 0; i < 4; ++i)
#pragma unroll
        for (int j = 0; j < 4; ++j) acc[i][j] = (f32x4)(0.0f);

    uint4 rau[2];
    uint4 rbu[2];

    auto loadA = [&](int k0) {
        const ushort* xp = X + (size_t)(m0g + arow) * DIM + k0 + apair * 16;
        rau[0] = *(const uint4*)xp;
        rau[1] = *(const uint4*)(xp + 8);
    };
    auto loadB = [&](int k0) {
        const ushort* wp0 = Wp + (size_t)(k0 + bkk) * DIM + n0 + bn8;
        rbu[0] = *(const uint4*)wp0;
        rbu[1] = *(const uint4*)(wp0 + DIM);
    };
    auto storeA = [&](int buf) {
        *(uint4*)&As[buf][adst]     = rau[0];
        *(uint4*)&As[buf][adst + 8] = rau[1];
    };
    auto storeB = [&](int buf) {
        ushort t0[8], t1[8];
        *(uint4*)t0 = rbu[0];
        *(uint4*)t1 = rbu[1];
#pragma unroll
        for (int j = 0; j < 8; ++j) {
            const int rr = bn8 + j;
            const int R = rr & 63, half = rr >> 6;
            const int gx = (((half << 2) + bkg) ^ (R & 7) ^ (R >> 3)) & 7;
            *(unsigned int*)&Bs[buf][R * 64 + gx * 8 + bo] =
                (unsigned int)t0[j] | ((unsigned int)t1[j] << 16);
        }
    };

    loadA(0); loadB(0);
    storeA(0); storeB(0);
    __syncthreads();

    for (int k = 0; k < DIM / 32; ++k) {
        const int cur = k & 1;
        const bool hn = (k + 1) < DIM / 32;
        if (hn) { loadA((k + 1) * 32); loadB((k + 1) * 32); }

        short8 b[4];
#pragma unroll
        for (int j = 0; j < 4; ++j) {
            const int rrn = wn + j * 16 + l16;
            const int R = rrn & 63, half = rrn >> 6;
            const int gx = (((half << 2) + quad) ^ (R & 7) ^ (R >> 3)) & 7;
            b[j] = *(const short8*)&Bs[cur][R * 64 + gx * 8];
        }
#pragma unroll
        for (int i = 0; i < 4; ++i) {
            const int rr = wm + i * 16 + l16;
            const int ps = (quad >> 1) ^ ((rr >> 3) & 1);
            const int col = ps * 16 + (quad & 1) * 8;
            short8 a = *(const short8*)&As[cur][rr * LSTR + col];
#pragma unroll
            for (int j = 0; j < 4; ++j)
                acc[i][j] = __builtin_amdgcn_mfma_f32_16x16x32_bf16(a, b[j], acc[i][j], 0, 0, 0);
        }
        if (hn) { storeA(cur ^ 1); storeB(cur ^ 1); }
        __syncthreads();
    }

#pragma unroll
    for (int j = 0; j < 4; ++j) {
        const int col = n0 + wn + j * 16 + l16;
        const float bv = dt ? ((const float*)Bp)[col] : bf2f(((const ushort*)Bp)[col]);
#pragma unroll
        for (int i = 0; i < 4; ++i)
#pragma unroll
            for (int r = 0; r < 4; ++r) {
                const int row = m0g + wm + i * 16 + quad * 4 + r;
                const size_t o = (size_t)row * DIM + col;
                const float val = acc[i][j][r] + bv;
                if (Y) Y[o] = val;
                if (yh) {
                    const ushort hv = f2bf(val);
                    yh[o] = hv;
                    yl[o] = f2bf(val - bf2f(hv));
                }
            }
    }
}

// ===========================================================================
// Merged output projections, 64-row m-tiles. grid (12, 40).
// X = 2560 contiguous f32 rows (oA 1280 + oC 1280), hi/lo split A.
// Segments: mt<16 a_out, <20 a_addout, <36 c_out, else c_addout.
// ===========================================================================
struct OutP {
    const float* X;
    const void* W[4]; const void* B[4];
    void* out;
};

__global__ __launch_bounds__(256) void gemm_out_v3(OutP p, const int* __restrict__ dflag)
{
    __shared__ __align__(16) ushort Ah[2][64 * LSTR];
    __shared__ __align__(16) ushort Al[2][64 * LSTR];
    __shared__ __align__(16) ushort Bs[2][64 * 64];
    const int dt = dflag[0];
    const int n0 = blockIdx.x * 128;
    const int mt = blockIdx.y;
    const int seg = (mt < 16) ? 0 : (mt < 20) ? 1 : (mt < 36) ? 2 : 3;
    const void* Wp = p.W[seg];
    const void* Bp = p.B[seg];
    const int m0 = mt * 64;

    const int t = threadIdx.x;
    const int wave = t >> 6, lane = t & 63;
    const int quad = lane >> 4, l16 = lane & 15;
    const int wm = (wave >> 1) * 32, wn = (wave & 1) * 64;

    const int arow = t >> 2, ag = t & 3;
    const int apg = ag >> 1, asub = ag & 1;
    const int aps = apg ^ ((arow >> 3) & 1);
    const int adst = arow * LSTR + aps * 16 + asub * 8;
    const int bn8 = (t & 15) << 3, bkk = (t >> 4) << 1;
    const int bkg = bkk >> 3, bo = bkk & 7;

    f32x4 acc[2][4];
#pragma unroll
    for (int i = 0; i < 2; ++i)
#pragma unroll
        for (int j = 0; j < 4; ++j) acc[i][j] = (f32x4)(0.0f);

    float4 raf[2];
    float4 rbf[4]; uint4 rbu[2];

    auto loadA = [&](int k0) {
        const float* xp = p.X + (size_t)(m0 + arow) * DIM + k0 + ag * 8;
        raf[0] = *(const float4*)xp;
        raf[1] = *(const float4*)(xp + 4);
    };
    auto loadB = [&](int k0) {
        const size_t off = (size_t)(k0 + bkk) * DIM + n0 + bn8;
        if (dt) {
            const float* wp0 = (const float*)Wp + off;
            rbf[0] = *(const float4*)wp0;         rbf[1] = *(const float4*)(wp0 + 4);
            rbf[2] = *(const float4*)(wp0 + DIM); rbf[3] = *(const float4*)(wp0 + DIM + 4);
        } else {
            const ushort* wp0 = (const ushort*)Wp + off;
            rbu[0] = *(const uint4*)wp0;
            rbu[1] = *(const uint4*)(wp0 + DIM);
        }
    };
    auto storeA = [&](int buf) {
        ushort hi[8], lo[8];
        const float* xs = (const float*)raf;
#pragma unroll
        for (int i = 0; i < 8; ++i) {
            hi[i] = f2bf(xs[i]);
            lo[i] = f2bf(xs[i] - bf2f(hi[i]));
        }
        *(uint4*)&Ah[buf][adst] = *(uint4*)&hi[0];
        *(uint4*)&Al[buf][adst] = *(uint4*)&lo[0];
    };
    auto storeB = [&](int buf) {
        ushort t0[8], t1[8];
        if (dt) {
            const float* f = (const float*)rbf;
#pragma unroll
            for (int j = 0; j < 8; ++j) { t0[j] = f2bf(f[j]); t1[j] = f2bf(f[8 + j]); }
        } else {
            *(uint4*)t0 = rbu[0];
            *(uint4*)t1 = rbu[1];
        }
#pragma unroll
        for (int j = 0; j < 8; ++j) {
            const int rr = bn8 + j;
            const int R = rr & 63, half = rr >> 6;
            const int gx = (((half << 2) + bkg) ^ (R & 7) ^ (R >> 3)) & 7;
            *(unsigned int*)&Bs[buf][R * 64 + gx * 8 + bo] =
                (unsigned int)t0[j] | ((unsigned int)t1[j] << 16);
        }
    };

    loadA(0); loadB(0);
    storeA(0); storeB(0);
    __syncthreads();

    for (int k = 0; k < DIM / 32; ++k) {
        const int cur = k & 1;
        const bool hn = (k + 1) < DIM / 32;
        if (hn) { loadA((k + 1) * 32); loadB((k + 1) * 32); }

        short8 b[4];
#pragma unroll
        for (int j = 0; j < 4; ++j) {
            const int rrn = wn + j * 16 + l16;
            const int R = rrn & 63, half = rrn >> 6;
            const int gx = (((half << 2) + quad) ^ (R & 7) ^ (R >> 3)) & 7;
            b[j] = *(const short8*)&Bs[cur][R * 64 + gx * 8];
        }
#pragma unroll
        for (int i = 0; i < 2; ++i) {
            const int rr = wm + i * 16 + l16;
            const int ps = (quad >> 1) ^ ((rr >> 3) & 1);
            const int col = ps * 16 + (quad & 1) * 8;
            short8 ah = *(const short8*)&Ah[cur][rr * LSTR + col];
            short8 al = *(const short8*)&Al[cur][rr * LSTR + col];
#pragma unroll
            for (int j = 0; j < 4; ++j) {
                acc[i][j] = __builtin_amdgcn_mfma_f32_16x16x32_bf16(ah, b[j], acc[i][j], 0, 0, 0);
                acc[i][j] = __builtin_amdgcn_mfma_f32_16x16x32_bf16(al, b[j], acc[i][j], 0, 0, 0);
            }
        }
        if (hn) { storeA(cur ^ 1); storeB(cur ^ 1); }
        __syncthreads();
    }

#pragma unroll
    for (int j = 0; j < 4; ++j) {
        const int col = n0 + wn + j * 16 + l16;
        const float bv = dt ? ((const float*)Bp)[col] : bf2f(((const ushort*)Bp)[col]);
#pragma unroll
        for (int i = 0; i < 2; ++i)
#pragma unroll
            for (int r = 0; r < 4; ++r) {
                const int grow = m0 + wm + i * 16 + quad * 4 + r;
                const size_t o = (size_t)grow * DIM + col;
                const float val = acc[i][j][r] + bv;
                if (dt) ((float*)p.out)[o] = val;
                else    ((ushort*)p.out)[o] = f2bf(val);
            }
    }
}

// ---------------------------------------------------------------------------
// RoPE kernels. pe flat layout: s*128 + i*4 + {cos,-sin,sin,cos}.
// ---------------------------------------------------------------------------
__device__ __forceinline__ void pe_load(const void* pe, int dt, size_t off,
                                        float& c00, float& c01, float& c10, float& c11)
{
    if (dt) {
        float4 pv = *(const float4*)((const float*)pe + off);
        c00 = pv.x; c01 = pv.y; c10 = pv.z; c11 = pv.w;
    } else {
        const ushort* pp = (const ushort*)pe + off;
        c00 = bf2f(pp[0]); c01 = bf2f(pp[1]); c10 = bf2f(pp[2]); c11 = bf2f(pp[3]);
    }
}

__global__ __launch_bounds__(256) void rope_f32_inplace(
    float* __restrict__ buf, const void* __restrict__ pe,
    const int* __restrict__ dflag, int S)
{
    const int dt = dflag[0];
    int idx = blockIdx.x * 256 + threadIdx.x;
    if (idx >= S * 768) return;
    int s = idx / 768, pp = idx - s * 768;
    int col = pp << 1, i = pp & 31;
    float* bp = buf + (size_t)s * DIM + col;
    float x0 = bp[0], x1 = bp[1];
    float c00, c01, c10, c11;
    pe_load(pe, dt, (size_t)s * 128 + i * 4, c00, c01, c10, c11);
    bp[0] = c00 * x0 + c01 * x1;
    bp[1] = c10 * x0 + c11 * x1;
}

__global__ __launch_bounds__(256) void rope_f32_to_split(
    const float* __restrict__ src, const void* __restrict__ pe,
    ushort* __restrict__ dh, ushort* __restrict__ dl,
    const int* __restrict__ dflag, int S)
{
    const int dt = dflag[0];
    int idx = blockIdx.x * 256 + threadIdx.x;
    if (idx >= S * 768) return;
    int s = idx / 768, pp = idx - s * 768;
    int col = pp << 1, i = pp & 31;
    float2 xv = *(const float2*)(src + (size_t)s * DIM + col);
    float c00, c01, c10, c11;
    pe_load(pe, dt, (size_t)s * 128 + i * 4, c00, c01, c10, c11);
    float y0 = c00 * xv.x + c01 * xv.y;
    float y1 = c10 * xv.x + c11 * xv.y;
    ushort h0 = f2bf(y0), h1 = f2bf(y1);
    ushort l0 = f2bf(y0 - bf2f(h0)), l1 = f2bf(y1 - bf2f(h1));
    *(unsigned int*)(dh + (size_t)s * DIM + col) = (unsigned int)h0 | ((unsigned int)h1 << 16);
    *(unsigned int*)(dl + (size_t)s * DIM + col) = (unsigned int)l0 | ((unsigned int)l1 << 16);
}

__global__ __launch_bounds__(256) void rope_in_to_f32(
    const void* __restrict__ src, const void* __restrict__ pe,
    float* __restrict__ dst, const int* __restrict__ dflag, int S)
{
    const int dt = dflag[0];
    int idx = blockIdx.x * 256 + threadIdx.x;
    if (idx >= S * 768) return;
    int s = idx / 768, pp = idx - s * 768;
    int col = pp << 1, i = pp & 31;
    float x0, x1;
    if (dt) {
        float2 xv = *(const float2*)((const float*)src + (size_t)s * DIM + col);
        x0 = xv.x; x1 = xv.y;
    } else {
        const ushort* sp = (const ushort*)src + (size_t)s * DIM + col;
        x0 = bf2f(sp[0]); x1 = bf2f(sp[1]);
    }
    float c00, c01, c10, c11;
    pe_load(pe, dt, (size_t)s * 128 + i * 4, c00, c01, c10, c11);
    float* dp = dst + (size_t)s * DIM + col;
    dp[0] = c00 * x0 + c01 * x1;
    dp[1] = c10 * x0 + c11 * x1;
}

// ---------------------------------------------------------------------------
// V transpose+split: f32 [seq][DIM] -> hi/lo bf16 [h*64+d][seq].
// ---------------------------------------------------------------------------
__global__ __launch_bounds__(256) void vtrans_split(
    const float* __restrict__ V, ushort* __restrict__ Vth, ushort* __restrict__ Vtl,
    int seq)
{
    __shared__ unsigned int tile[64 * 65];
    const int s0 = blockIdx.x * 64;
    const int h = blockIdx.y;
    const int t = threadIdx.x;
#pragma unroll
    for (int it = 0; it < 16; ++it) {
        const int sl = (t >> 6) + (it << 2);
        const int d = t & 63;
        const float v = V[(size_t)(s0 + sl) * DIM + h * HD + d];
        const ushort hv = f2bf(v);
        const ushort lv = f2bf(v - bf2f(hv));
        tile[d * 65 + sl] = (unsigned int)hv | ((unsigned int)lv << 16);
    }
    __syncthreads();
    const int d = t >> 2, cc = (t & 3) << 4;
    ushort th[16], tl[16];
#pragma unroll
    for (int j = 0; j < 16; ++j) {
        const unsigned int w = tile[d * 65 + cc + j];
        th[j] = (ushort)w;
        tl[j] = (ushort)(w >> 16);
    }
    const size_t off = (size_t)(h * HD + d) * seq + s0 + cc;
    *(uint4*)(Vth + off)     = *(uint4*)&th[0];
    *(uint4*)(Vth + off + 8) = *(uint4*)&th[8];
    *(uint4*)(Vtl + off)     = *(uint4*)&tl[0];
    *(uint4*)(Vtl + off + 8) = *(uint4*)&tl[8];
}

// ---------------------------------------------------------------------------
// MFMA flash attention, KV-split (grid.z = 2). Q staged from f32 (one-time
// per-block hi/lo conversion); K/V from pre-split bf16 planes. Writes
// unnormalized O partials + (m,l); merge kernel combines.
// ---------------------------------------------------------------------------
__device__ __forceinline__ int swz(int row, int col) {
    return row * 64 + ((((col >> 3) ^ row) & 7) << 3) + (col & 7);
}
__device__ __forceinline__ short8 ldfrag(const ushort* plane, int row, int col) {
    return *(const short8*)&plane[swz(row, col)];
}

struct AttnP {
    const float* Qf;
    const ushort *Kh, *Kl, *Vth, *Vtl;
    float* Op0;     // z=0 partial plane (aliases a dead f32 buffer)
    float* Op1;     // z=1 partial plane
    float2* Ml;     // [2][NH][SEQ] (m,l)
    int kvchunk;    // kv positions per z-split (640)
    int kvstride;   // seq stride of Vt layout (SEQ)
};

__global__ __launch_bounds__(256) void attn_mfma_split(AttnP p)
{
    __shared__ ushort Qh_[4096], Ql_[4096];
    __shared__ ushort Kh_[4096], Kl_[4096];
    __shared__ ushort Vh_[4096], Vl_[4096];

    const int q0 = blockIdx.x * 64;
    const int h = blockIdx.y;
    const int z = blockIdx.z;
    const int t = threadIdx.x;
    const int wave = t >> 6, lane = t & 63;
    const int quad = lane >> 4, l16 = lane & 15;
    const int wq0 = wave * 16;

    const int srow = t >> 2, c0 = (t & 3) << 4;
    const int g0 = c0 >> 3;
    const int p0 = ((g0 ^ (srow & 7)) & 7) << 3;
    const int p1 = (((g0 + 1) ^ (srow & 7)) & 7) << 3;

    {
        const float* src = p.Qf + (size_t)(q0 + srow) * DIM + h * HD + c0;
        float x[16];
        *(float4*)&x[0]  = *(const float4*)(src);
        *(float4*)&x[4]  = *(const float4*)(src + 4);
        *(float4*)&x[8]  = *(const float4*)(src + 8);
        *(float4*)&x[12] = *(const float4*)(src + 12);
        ushort hi[16], lo[16];
#pragma unroll
        for (int i = 0; i < 16; ++i) {
            hi[i] = f2bf(x[i]);
            lo[i] = f2bf(x[i] - bf2f(hi[i]));
        }
        *(uint4*)&Qh_[srow * 64 + p0] = *(uint4*)&hi[0];
        *(uint4*)&Qh_[srow * 64 + p1] = *(uint4*)&hi[8];
        *(uint4*)&Ql_[srow * 64 + p0] = *(uint4*)&lo[0];
        *(uint4*)&Ql_[srow * 64 + p1] = *(uint4*)&lo[8];
    }
    // Within-wave store->read: wave w stages rows 16w..16w+15 and reads only
    // those rows (lgkmcnt-ordered, no barrier needed).
    short8 qfh[2], qfl[2];
#pragma unroll
    for (int c = 0; c < 2; ++c) {
        qfh[c] = ldfrag(Qh_, wq0 + l16, c * 32 + quad * 8);
        qfl[c] = ldfrag(Ql_, wq0 + l16, c * 32 + quad * 8);
    }

    float m_[4], l_[4];
#pragma unroll
    for (int r = 0; r < 4; ++r) { m_[r] = -3e38f; l_[r] = 0.0f; }
    f32x4 Oacc[4];
#pragma unroll
    for (int j = 0; j < 4; ++j) Oacc[j] = (f32x4)(0.0f);

    const int kvbeg = z * p.kvchunk;
    for (int kt = 0; kt < p.kvchunk; kt += 64) {
        const int kv0 = kvbeg + kt;
        __syncthreads();
        {
            const size_t off = (size_t)(kv0 + srow) * DIM + h * HD + c0;
            *(uint4*)&Kh_[srow * 64 + p0] = *(const uint4*)(p.Kh + off);
            *(uint4*)&Kh_[srow * 64 + p1] = *(const uint4*)(p.Kh + off + 8);
            *(uint4*)&Kl_[srow * 64 + p0] = *(const uint4*)(p.Kl + off);
            *(uint4*)&Kl_[srow * 64 + p1] = *(const uint4*)(p.Kl + off + 8);
        }
        {
            const size_t off = (size_t)(h * HD + srow) * p.kvstride + kv0 + c0;
            *(uint4*)&Vh_[srow * 64 + p0] = *(const uint4*)(p.Vth + off);
            *(uint4*)&Vh_[srow * 64 + p1] = *(const uint4*)(p.Vth + off + 8);
            *(uint4*)&Vl_[srow * 64 + p0] = *(const uint4*)(p.Vtl + off);
            *(uint4*)&Vl_[srow * 64 + p1] = *(const uint4*)(p.Vtl + off + 8);
        }
        __syncthreads();

        f32x4 S[4];
#pragma unroll
        for (int j = 0; j < 4; ++j) S[j] = (f32x4)(0.0f);
#pragma unroll
        for (int c = 0; c < 2; ++c) {
#pragma unroll
            for (int j = 0; j < 4; ++j) {
                short8 bh = ldfrag(Kh_, j * 16 + l16, c * 32 + quad * 8);
                short8 bl = ldfrag(Kl_, j * 16 + l16, c * 32 + quad * 8);
                S[j] = __builtin_amdgcn_mfma_f32_16x16x32_bf16(qfh[c], bh, S[j], 0, 0, 0);
                S[j] = __builtin_amdgcn_mfma_f32_16x16x32_bf16(qfl[c], bh, S[j], 0, 0, 0);
                S[j] = __builtin_amdgcn_mfma_f32_16x16x32_bf16(qfh[c], bl, S[j], 0, 0, 0);
            }
        }
#pragma unroll
        for (int j = 0; j < 4; ++j)
#pragma unroll
            for (int r = 0; r < 4; ++r) S[j][r] *= 0.125f;

        float alpha[4];
#pragma unroll
        for (int r = 0; r < 4; ++r) {
            float mx = fmaxf(fmaxf(S[0][r], S[1][r]), fmaxf(S[2][r], S[3][r]));
            mx = fmaxf(mx, __shfl_xor(mx, 1));
            mx = fmaxf(mx, __shfl_xor(mx, 2));
            mx = fmaxf(mx, __shfl_xor(mx, 4));
            mx = fmaxf(mx, __shfl_xor(mx, 8));
            float mn = fmaxf(m_[r], mx);
            alpha[r] = __expf(m_[r] - mn);
            m_[r] = mn;
            float rs = 0.0f;
#pragma unroll
            for (int j = 0; j < 4; ++j) {
                float pv = __expf(S[j][r] - mn);
                S[j][r] = pv;
                rs += pv;
            }
            rs += __shfl_xor(rs, 1);
            rs += __shfl_xor(rs, 2);
            rs += __shfl_xor(rs, 4);
            rs += __shfl_xor(rs, 8);
            l_[r] = l_[r] * alpha[r] + rs;
        }
#pragma unroll
        for (int j = 0; j < 4; ++j)
#pragma unroll
            for (int r = 0; r < 4; ++r) Oacc[j][r] *= alpha[r];

        {
            const int prow = wq0 + quad * 4;
#pragma unroll
            for (int j = 0; j < 4; ++j)
#pragma unroll
                for (int r = 0; r < 4; ++r) {
                    float pv = S[j][r];
                    ushort ph = f2bf(pv);
                    ushort pl = f2bf(pv - bf2f(ph));
                    int idx = swz(prow + r, j * 16 + l16);
                    Qh_[idx] = ph;
                    Ql_[idx] = pl;
                }
        }

#pragma unroll
        for (int c = 0; c < 2; ++c) {
            short8 pah = ldfrag(Qh_, wq0 + l16, c * 32 + quad * 8);
            short8 pal = ldfrag(Ql_, wq0 + l16, c * 32 + quad * 8);
#pragma unroll
            for (int jn = 0; jn < 4; ++jn) {
                short8 vbh = ldfrag(Vh_, jn * 16 + l16, c * 32 + quad * 8);
                short8 vbl = ldfrag(Vl_, jn * 16 + l16, c * 32 + quad * 8);
                Oacc[jn] = __builtin_amdgcn_mfma_f32_16x16x32_bf16(pah, vbh, Oacc[jn], 0, 0, 0);
                Oacc[jn] = __builtin_amdgcn_mfma_f32_16x16x32_bf16(pal, vbh, Oacc[jn], 0, 0, 0);
                Oacc[jn] = __builtin_amdgcn_mfma_f32_16x16x32_bf16(pah, vbl, Oacc[jn], 0, 0, 0);
            }
        }
    }

    float* Opz = z ? p.Op1 : p.Op0;
#pragma unroll
    for (int r = 0; r < 4; ++r) {
        const int rowq = q0 + wq0 + quad * 4 + r;
        if (l16 == 0)
            p.Ml[((size_t)z * NH + h) * SEQ + rowq] = make_float2(m_[r], l_[r]);
#pragma unroll
        for (int jn = 0; jn < 4; ++jn)
            Opz[(size_t)rowq * DIM + h * HD + jn * 16 + l16] = Oacc[jn][r];
    }
}

// Merge NSPLIT=2 partials. Elementwise-safe when out aliases Op0/Op1.
__global__ __launch_bounds__(256) void attn_merge(
    const float* __restrict__ Op0, const float* __restrict__ Op1,
    const float2* __restrict__ Ml,
    float* __restrict__ out, const float* __restrict__ addto, int qlen)
{
    const int idx = blockIdx.x * 256 + threadIdx.x;
    if (idx >= qlen * 384) return;
    const int rowq = idx / 384;
    const int c4 = (idx - rowq * 384) << 2;
    const float2 a = Ml[(size_t)(c4 >> 6) * SEQ + rowq];
    const float2 b = Ml[(size_t)(NH + (c4 >> 6)) * SEQ + rowq];
    const float ms = fmaxf(a.x, b.x);
    const float s0 = __expf(a.x - ms), s1 = __expf(b.x - ms);
    const float inv = 1.0f / (s0 * a.y + s1 * b.y);
    const float4 o0 = *(const float4*)&Op0[(size_t)rowq * DIM + c4];
    const float4 o1 = *(const float4*)&Op1[(size_t)rowq * DIM + c4];
    float4 r;
    r.x = (s0 * o0.x + s1 * o1.x) * inv;
    r.y = (s0 * o0.y + s1 * o1.y) * inv;
    r.z = (s0 * o0.z + s1 * o1.z) * inv;
    r.w = (s0 * o0.w + s1 * o1.w) * inv;
    if (addto) {
        const float4 c = *(const float4*)&addto[(size_t)rowq * DIM + c4];
        r.x += c.x; r.y += c.y; r.z += c.z; r.w += c.w;
    }
    *(float4*)&out[(size_t)rowq * DIM + c4] = r;
}

// ---------------------------------------------------------------------------
extern "C" void kernel_launch(void* const* d_in, const int* in_sizes, int n_in,
                              void* d_out, int out_size, void* d_ws, size_t ws_size,
                              hipStream_t stream) {
    (void)in_sizes; (void)n_in; (void)out_size; (void)ws_size;
    const void* hs   = d_in[0];
    const void* ehs  = d_in[1];
    const void* hsc  = d_in[2];
    const void* ehsc = d_in[3];
    const void* i2q  = d_in[4];
    const void* pe   = d_in[5];
#define W_(i) ((const void*)d_in[i])

    int*   flag = (int*)d_ws;
    float* fb = (float*)((char*)d_ws + 256);
    float* q1 = fb;            // C's q f32 (roped in place)
    float* k1 = q1 + SD;       // C's k f32; later cross-q f32 (qx)
    float* v1 = k1 + SD;       // A's v f32; later attn partial plane 0
    float* vC = v1 + SD;       // C's v f32; later attn partial plane 1 (C/X)
    float* oA = vC + SD;       // out-proj X rows 0..1279; attnA partial plane 1
    float* oC = oA + SD;       // MUST be oA+SD; A's q f32 (qA) until mergeC
    ushort* kh  = (ushort*)(oC + SD);  // K split planes, SD ushorts each
    ushort* klo = kh + SD;
    ushort* vth = klo + SD;    // V^T split planes
    ushort* vtl = vth + SD;
    ushort* Wbf = vtl + SD;    // 12 * DIM*DIM bf16 weights
    ushort* Xbf = Wbf + 12 * WSZ;  // 2 * SEQ*DIM bf16 inputs
    float2* Ml = (float2*)(Xbf + 2 * SD);  // 2*NH*SEQ float2
    float* qA = oC;            // A's q f32 (dead after attnA; oC written at mergeC)
    float* qx = k1;            // cross-q f32 (written after k1 is consumed)

    dim3 blk(256);
    detect_dtype<<<1, blk, 0, stream>>>(hs, flag);

    // ---- one-time bf16 conversion: 12 QKV weights + 4 X inputs ----
    {
        CvtP cp;
        const int wsrc[12] = {6, 8, 10, 12, 14, 16, 22, 24, 26, 28, 30, 32};
        for (int j = 0; j < 12; ++j) {
            cp.src[j] = W_(wsrc[j]);
            cp.dst[j] = Wbf + (size_t)j * WSZ;
            cp.n8[j] = (int)(WSZ / 8);
        }
        cp.src[12] = hs;   cp.dst[12] = Xbf;                cp.n8[12] = (int)(IDSZ / 8);
        cp.src[13] = ehs;  cp.dst[13] = Xbf + IDSZ;         cp.n8[13] = (int)((size_t)TXT * DIM / 8);
        cp.src[14] = hsc;  cp.dst[14] = Xbf + SD;           cp.n8[14] = (int)(IDSZ / 8);
        cp.src[15] = ehsc; cp.dst[15] = Xbf + SD + IDSZ;    cp.n8[15] = (int)((size_t)TXT * DIM / 8);
        convert_bf16<<<dim3((int)(WSZ / 8 + 255) / 256, 16), blk, 0, stream>>>(cp, flag);
    }

    // ---- merged QKV for both streams ----
    QKV3P qp;
    qp.Xb = Xbf;
    qp.Wb = Wbf;
    {
        const int bsrc[12] = {7, 9, 11, 13, 15, 17, 23, 25, 27, 29, 31, 33};
        for (int j = 0; j < 12; ++j) qp.B[j] = W_(bsrc[j]);
    }
    for (int j = 0; j < 6; ++j) { qp.Y[j] = nullptr; qp.Yh[j] = nullptr; qp.Yl[j] = nullptr; }
    qp.Y[0] = qA;                     // A q: f32 (attn stages from f32)
    qp.Yh[1] = kh;  qp.Yl[1] = klo;   // A k: split planes only
    qp.Y[2] = v1;                     // A v: f32 for vtrans
    qp.Y[3] = q1;                     // C q: f32 for rope
    qp.Y[4] = k1;                     // C k: f32 for rope
    qp.Y[5] = vC;                     // C v: f32 for vtrans
    gemm_qkv_v4<<<dim3(36, 20), blk, 0, stream>>>(qp, flag);

    auto ATTN = [&](const float* Qfp, int qblocks, float* Op0, float* Op1) {
        AttnP p;
        p.Qf = Qfp;
        p.Kh = kh;  p.Kl = klo;
        p.Vth = vth; p.Vtl = vtl;
        p.Op0 = Op0; p.Op1 = Op1; p.Ml = Ml;
        p.kvchunk = SEQ / 2; p.kvstride = SEQ;
        attn_mfma_split<<<dim3(qblocks, NH, 2), blk, 0, stream>>>(p);
    };

    // ---- stream A attention ----
    vtrans_split<<<dim3(SEQ / 64, NH), blk, 0, stream>>>(v1, vth, vtl, SEQ);
    ATTN(qA, SEQ / 64, v1, oA);                      // v1 dead post-vtrans; oA not yet live
    attn_merge<<<(SEQ * 384 + 255) / 256, blk, 0, stream>>>(v1, oA, Ml, oA, nullptr, SEQ);

    // ---- stream C prep ----
    rope_f32_inplace<<<(SEQ * 768 + 255) / 256, blk, 0, stream>>>(q1, pe, flag, SEQ);
    rope_f32_to_split<<<(SEQ * 768 + 255) / 256, blk, 0, stream>>>(k1, pe, kh, klo, flag, SEQ);
    vtrans_split<<<dim3(SEQ / 64, NH), blk, 0, stream>>>(vC, vth, vtl, SEQ);
    rope_in_to_f32<<<(IMG * 768 + 255) / 256, blk, 0, stream>>>(i2q, pe, qx, flag, IMG);

    // ---- stream C self attention ----
    ATTN(q1, SEQ / 64, v1, vC);                      // vC dead post-vtransC
    attn_merge<<<(SEQ * 384 + 255) / 256, blk, 0, stream>>>(v1, vC, Ml, oC, nullptr, SEQ);

    // ---- cross attention; merge folds oA += cross ----
    ATTN(qx, IMG / 64, v1, vC);
    attn_merge<<<(IMG * 384 + 255) / 256, blk, 0, stream>>>(v1, vC, Ml, oA, oA, IMG);

    OutP op;
    op.X = oA;
    op.W[0] = W_(18); op.B[0] = W_(19);
    op.W[1] = W_(20); op.B[1] = W_(21);
    op.W[2] = W_(34); op.B[2] = W_(35);
    op.W[3] = W_(36); op.B[3] = W_(37);
    op.out = d_out;
    gemm_out_v3<<<dim3(12, 40), blk, 0, stream>>>(op, flag);
#undef W_
}

// Round 4
// 554.959 us; speedup vs baseline: 1.2936x; 1.1801x over previous
//
#include <hip/hip_runtime.h>

#define DIM 1536
#define IMG 1024
#define TXT 256
#define SEQ 1280
#define NH 24
#define HD 64
#define SD ((size_t)SEQ * DIM)
#define IDSZ ((size_t)IMG * DIM)
#define WSZ ((size_t)DIM * DIM)

typedef __attribute__((ext_vector_type(8))) short short8;
typedef __attribute__((ext_vector_type(4))) float f32x4;

__device__ __forceinline__ float bf2f(ushort u) {
    union { unsigned int i; float f; } v; v.i = ((unsigned int)u) << 16; return v.f;
}
__device__ __forceinline__ ushort f2bf(float f) {
    union { unsigned int i; float f; } v; v.f = f;
    unsigned int u = v.i;
    u += 0x7fffu + ((u >> 16) & 1u);
    return (ushort)(u >> 16);
}

// ---------------------------------------------------------------------------
// Input-dtype detector (flag=1 -> fp32 underneath, flag=0 -> bf16).
// ---------------------------------------------------------------------------
__global__ __launch_bounds__(256) void detect_dtype(const void* __restrict__ p,
                                                    int* __restrict__ flag)
{
    __shared__ int cnt;
    if (threadIdx.x == 0) cnt = 0;
    __syncthreads();
    const ushort* u = (const ushort*)p;
    int local = 0;
    for (int i = threadIdx.x; i < 2048; i += 256) {
        ushort v = u[2 * i];
        int e = (v >> 7) & 0xFF;
        if (e >= 0xC0) local++;
    }
    atomicAdd(&cnt, local);
    __syncthreads();
    if (threadIdx.x == 0) flag[0] = (cnt > 16) ? 1 : 0;
}

// ---------------------------------------------------------------------------
// One-time bf16 conversion: 16 weights (12 qkv + 4 out) + 4 X inputs.
// ---------------------------------------------------------------------------
struct CvtP {
    const void* src[20];
    ushort* dst[20];
    int n8[20];
};

__global__ __launch_bounds__(256) void convert_bf16(CvtP p, const int* __restrict__ dflag)
{
    const int a = blockIdx.y;
    const int i = blockIdx.x * 256 + threadIdx.x;
    if (i >= p.n8[a]) return;
    const size_t off = (size_t)i * 8;
    uint4 o;
    if (dflag[0]) {
        const float* s = (const float*)p.src[a] + off;
        const float4 f0 = *(const float4*)s;
        const float4 f1 = *(const float4*)(s + 4);
        ushort t[8];
        t[0] = f2bf(f0.x); t[1] = f2bf(f0.y); t[2] = f2bf(f0.z); t[3] = f2bf(f0.w);
        t[4] = f2bf(f1.x); t[5] = f2bf(f1.y); t[6] = f2bf(f1.z); t[7] = f2bf(f1.w);
        o = *(uint4*)t;
    } else {
        o = *(const uint4*)((const ushort*)p.src[a] + off);
    }
    *(uint4*)(p.dst[a] + off) = o;
}

#define LSTR 40

// ===========================================================================
// Merged QKV GEMM over pre-converted bf16 X and W. grid (36, 20).
// B plane: 128 n-rows folded into 64 LDS rows of 64 ushorts, granule XOR
// gx = ((half<<2)+g) ^ (R&7) ^ (R>>3).
// ===========================================================================
struct QKV3P {
    const ushort* Xb;    // [2][SEQ][DIM] bf16
    const ushort* Wb;    // [12][DIM][DIM] bf16, idx = str*6 + wsel + istxt*3
    const void* B[12];
    float* Y[6];
    ushort* Yh[6];
    ushort* Yl[6];
};

__global__ __launch_bounds__(256) void gemm_qkv_v4(QKV3P p, const int* __restrict__ dflag)
{
    __shared__ __align__(16) ushort As[2][128 * LSTR];
    __shared__ __align__(16) ushort Bs[2][64 * 64];
    const int dt = dflag[0];
    const int bx = blockIdx.x;
    const int wsel = bx / 12;
    const int n0 = (bx - wsel * 12) * 128;
    const int ys = blockIdx.y;
    const int str = (ys >= 10) ? 1 : 0;
    const int m0g = (ys - str * 10) * 128;
    const bool istxt = (m0g >= IMG);
    const int widx = str * 6 + wsel + (istxt ? 3 : 0);
    const ushort* X  = p.Xb + (size_t)str * SD;
    const ushort* Wp = p.Wb + (size_t)widx * WSZ;
    const void* Bp = p.B[widx];
    const int yidx = str * 3 + wsel;
    float*  Y  = p.Y[yidx];
    ushort* yh = p.Yh[yidx];
    ushort* yl = p.Yl[yidx];

    const int t = threadIdx.x;
    const int wave = t >> 6, lane = t & 63;
    const int quad = lane >> 4, l16 = lane & 15;
    const int wm = (wave >> 1) * 64, wn = (wave & 1) * 64;

    const int arow = t >> 1, apair = t & 1;
    const int bn8 = (t & 15) << 3, bkk = (t >> 4) << 1;
    const int aps = apair ^ ((arow >> 3) & 1);
    const int adst = arow * LSTR + aps * 16;
    const int bkg = bkk >> 3, bo = bkk & 7;

    f32x4 acc[4][4];
#pragma unroll
    for (int i = 0; i < 4; ++i)
#pragma unroll
        for (int j = 0; j < 4; ++j) acc[i][j] = (f32x4)(0.0f);

    uint4 rau[2];
    uint4 rbu[2];

    auto loadA = [&](int k0) {
        const ushort* xp = X + (size_t)(m0g + arow) * DIM + k0 + apair * 16;
        rau[0] = *(const uint4*)xp;
        rau[1] = *(const uint4*)(xp + 8);
    };
    auto loadB = [&](int k0) {
        const ushort* wp0 = Wp + (size_t)(k0 + bkk) * DIM + n0 + bn8;
        rbu[0] = *(const uint4*)wp0;
        rbu[1] = *(const uint4*)(wp0 + DIM);
    };
    auto storeA = [&](int buf) {
        *(uint4*)&As[buf][adst]     = rau[0];
        *(uint4*)&As[buf][adst + 8] = rau[1];
    };
    auto storeB = [&](int buf) {
        ushort t0[8], t1[8];
        *(uint4*)t0 = rbu[0];
        *(uint4*)t1 = rbu[1];
#pragma unroll
        for (int j = 0; j < 8; ++j) {
            const int rr = bn8 + j;
            const int R = rr & 63, half = rr >> 6;
            const int gx = (((half << 2) + bkg) ^ (R & 7) ^ (R >> 3)) & 7;
            *(unsigned int*)&Bs[buf][R * 64 + gx * 8 + bo] =
                (unsigned int)t0[j] | ((unsigned int)t1[j] << 16);
        }
    };

    loadA(0); loadB(0);
    storeA(0); storeB(0);
    __syncthreads();

    for (int k = 0; k < DIM / 32; ++k) {
        const int cur = k & 1;
        const bool hn = (k + 1) < DIM / 32;
        if (hn) { loadA((k + 1) * 32); loadB((k + 1) * 32); }

        short8 b[4];
#pragma unroll
        for (int j = 0; j < 4; ++j) {
            const int rrn = wn + j * 16 + l16;
            const int R = rrn & 63, half = rrn >> 6;
            const int gx = (((half << 2) + quad) ^ (R & 7) ^ (R >> 3)) & 7;
            b[j] = *(const short8*)&Bs[cur][R * 64 + gx * 8];
        }
#pragma unroll
        for (int i = 0; i < 4; ++i) {
            const int rr = wm + i * 16 + l16;
            const int ps = (quad >> 1) ^ ((rr >> 3) & 1);
            const int col = ps * 16 + (quad & 1) * 8;
            short8 a = *(const short8*)&As[cur][rr * LSTR + col];
#pragma unroll
            for (int j = 0; j < 4; ++j)
                acc[i][j] = __builtin_amdgcn_mfma_f32_16x16x32_bf16(a, b[j], acc[i][j], 0, 0, 0);
        }
        if (hn) { storeA(cur ^ 1); storeB(cur ^ 1); }
        __syncthreads();
    }

#pragma unroll
    for (int j = 0; j < 4; ++j) {
        const int col = n0 + wn + j * 16 + l16;
        const float bv = dt ? ((const float*)Bp)[col] : bf2f(((const ushort*)Bp)[col]);
#pragma unroll
        for (int i = 0; i < 4; ++i)
#pragma unroll
            for (int r = 0; r < 4; ++r) {
                const int row = m0g + wm + i * 16 + quad * 4 + r;
                const size_t o = (size_t)row * DIM + col;
                const float val = acc[i][j][r] + bv;
                if (Y) Y[o] = val;
                if (yh) {
                    const ushort hv = f2bf(val);
                    yh[o] = hv;
                    yl[o] = f2bf(val - bf2f(hv));
                }
            }
    }
}

// ===========================================================================
// Output projections from pre-split bf16 A planes (Xh/Xl, 2560 rows) and
// pre-converted bf16 weights. grid (12, 40), 64-row m-tiles.
// Segments: mt<16 a_out, <20 a_addout, <36 c_out, else c_addout.
// ===========================================================================
struct OutP {
    const ushort* Xh; const ushort* Xl;
    const ushort* Wb;    // 4 * WSZ bf16
    const void* B[4];
    void* out;
};

__global__ __launch_bounds__(256) void gemm_out_v4(OutP p, const int* __restrict__ dflag)
{
    __shared__ __align__(16) ushort Ah[2][64 * LSTR];
    __shared__ __align__(16) ushort Al[2][64 * LSTR];
    __shared__ __align__(16) ushort Bs[2][64 * 64];
    const int dt = dflag[0];
    const int n0 = blockIdx.x * 128;
    const int mt = blockIdx.y;
    const int seg = (mt < 16) ? 0 : (mt < 20) ? 1 : (mt < 36) ? 2 : 3;
    const ushort* Wp = p.Wb + (size_t)seg * WSZ;
    const void* Bp = p.B[seg];
    const int m0 = mt * 64;

    const int t = threadIdx.x;
    const int wave = t >> 6, lane = t & 63;
    const int quad = lane >> 4, l16 = lane & 15;
    const int wm = (wave >> 1) * 32, wn = (wave & 1) * 64;

    const int arow = t >> 2, ag = t & 3;
    const int apg = ag >> 1, asub = ag & 1;
    const int aps = apg ^ ((arow >> 3) & 1);
    const int adst = arow * LSTR + aps * 16 + asub * 8;
    const int bn8 = (t & 15) << 3, bkk = (t >> 4) << 1;
    const int bkg = bkk >> 3, bo = bkk & 7;

    f32x4 acc[2][4];
#pragma unroll
    for (int i = 0; i < 2; ++i)
#pragma unroll
        for (int j = 0; j < 4; ++j) acc[i][j] = (f32x4)(0.0f);

    uint4 rah, ral;
    uint4 rbu[2];

    auto loadA = [&](int k0) {
        const size_t off = (size_t)(m0 + arow) * DIM + k0 + ag * 8;
        rah = *(const uint4*)(p.Xh + off);
        ral = *(const uint4*)(p.Xl + off);
    };
    auto loadB = [&](int k0) {
        const ushort* wp0 = Wp + (size_t)(k0 + bkk) * DIM + n0 + bn8;
        rbu[0] = *(const uint4*)wp0;
        rbu[1] = *(const uint4*)(wp0 + DIM);
    };
    auto storeA = [&](int buf) {
        *(uint4*)&Ah[buf][adst] = rah;
        *(uint4*)&Al[buf][adst] = ral;
    };
    auto storeB = [&](int buf) {
        ushort t0[8], t1[8];
        *(uint4*)t0 = rbu[0];
        *(uint4*)t1 = rbu[1];
#pragma unroll
        for (int j = 0; j < 8; ++j) {
            const int rr = bn8 + j;
            const int R = rr & 63, half = rr >> 6;
            const int gx = (((half << 2) + bkg) ^ (R & 7) ^ (R >> 3)) & 7;
            *(unsigned int*)&Bs[buf][R * 64 + gx * 8 + bo] =
                (unsigned int)t0[j] | ((unsigned int)t1[j] << 16);
        }
    };

    loadA(0); loadB(0);
    storeA(0); storeB(0);
    __syncthreads();

    for (int k = 0; k < DIM / 32; ++k) {
        const int cur = k & 1;
        const bool hn = (k + 1) < DIM / 32;
        if (hn) { loadA((k + 1) * 32); loadB((k + 1) * 32); }

        short8 b[4];
#pragma unroll
        for (int j = 0; j < 4; ++j) {
            const int rrn = wn + j * 16 + l16;
            const int R = rrn & 63, half = rrn >> 6;
            const int gx = (((half << 2) + quad) ^ (R & 7) ^ (R >> 3)) & 7;
            b[j] = *(const short8*)&Bs[cur][R * 64 + gx * 8];
        }
#pragma unroll
        for (int i = 0; i < 2; ++i) {
            const int rr = wm + i * 16 + l16;
            const int ps = (quad >> 1) ^ ((rr >> 3) & 1);
            const int col = ps * 16 + (quad & 1) * 8;
            short8 ah = *(const short8*)&Ah[cur][rr * LSTR + col];
            short8 al = *(const short8*)&Al[cur][rr * LSTR + col];
#pragma unroll
            for (int j = 0; j < 4; ++j) {
                acc[i][j] = __builtin_amdgcn_mfma_f32_16x16x32_bf16(ah, b[j], acc[i][j], 0, 0, 0);
                acc[i][j] = __builtin_amdgcn_mfma_f32_16x16x32_bf16(al, b[j], acc[i][j], 0, 0, 0);
            }
        }
        if (hn) { storeA(cur ^ 1); storeB(cur ^ 1); }
        __syncthreads();
    }

#pragma unroll
    for (int j = 0; j < 4; ++j) {
        const int col = n0 + wn + j * 16 + l16;
        const float bv = dt ? ((const float*)Bp)[col] : bf2f(((const ushort*)Bp)[col]);
#pragma unroll
        for (int i = 0; i < 2; ++i)
#pragma unroll
            for (int r = 0; r < 4; ++r) {
                const int grow = m0 + wm + i * 16 + quad * 4 + r;
                const size_t o = (size_t)grow * DIM + col;
                const float val = acc[i][j][r] + bv;
                if (dt) ((float*)p.out)[o] = val;
                else    ((ushort*)p.out)[o] = f2bf(val);
            }
    }
}

// ---------------------------------------------------------------------------
// Fused prep: vtrans (both streams) + all three RoPE jobs in one launch.
// pe flat layout: s*128 + i*4 + {cos,-sin,sin,cos}.
// ---------------------------------------------------------------------------
__device__ __forceinline__ void pe_load(const void* pe, int dt, size_t off,
                                        float& c00, float& c01, float& c10, float& c11)
{
    if (dt) {
        float4 pv = *(const float4*)((const float*)pe + off);
        c00 = pv.x; c01 = pv.y; c10 = pv.z; c11 = pv.w;
    } else {
        const ushort* pp = (const ushort*)pe + off;
        c00 = bf2f(pp[0]); c01 = bf2f(pp[1]); c10 = bf2f(pp[2]); c11 = bf2f(pp[3]);
    }
}

struct PrepP {
    const float* v1; const float* vC;
    ushort *vthA, *vtlA, *vthC, *vtlC;
    float* q1;                        // C q, roped inplace
    const float* k1; ushort *khC, *kloC;
    const void* i2q; float* qx;       // cross q, roped to f32
    const void* pe;
};

#define VT_BLKS 960
#define RN0 (SEQ * 768)
#define RN1 (SEQ * 768)
#define RN2 (IMG * 768)

__global__ __launch_bounds__(256) void prep_fused(PrepP p, const int* __restrict__ dflag)
{
    __shared__ unsigned int tile[64 * 65];
    const int dt = dflag[0];
    const int bx = blockIdx.x;
    const int t = threadIdx.x;

    if (bx < VT_BLKS) {
        // ---- vtrans: z = bx/480 selects stream; f32 [seq][DIM] -> hi/lo [h*64+d][seq]
        const int z = bx / 480, rem = bx - z * 480;
        const int s0 = (rem % 20) * 64, h = rem / 20;
        const float* V = z ? p.vC : p.v1;
        ushort* Vth = z ? p.vthC : p.vthA;
        ushort* Vtl = z ? p.vtlC : p.vtlA;
#pragma unroll
        for (int it = 0; it < 16; ++it) {
            const int sl = (t >> 6) + (it << 2);
            const int d = t & 63;
            const float v = V[(size_t)(s0 + sl) * DIM + h * HD + d];
            const ushort hv = f2bf(v);
            const ushort lv = f2bf(v - bf2f(hv));
            tile[d * 65 + sl] = (unsigned int)hv | ((unsigned int)lv << 16);
        }
        __syncthreads();
        const int d = t >> 2, cc = (t & 3) << 4;
        ushort th[16], tl[16];
#pragma unroll
        for (int j = 0; j < 16; ++j) {
            const unsigned int w = tile[d * 65 + cc + j];
            th[j] = (ushort)w;
            tl[j] = (ushort)(w >> 16);
        }
        const size_t off = (size_t)(h * HD + d) * SEQ + s0 + cc;
        *(uint4*)(Vth + off)     = *(uint4*)&th[0];
        *(uint4*)(Vth + off + 8) = *(uint4*)&th[8];
        *(uint4*)(Vtl + off)     = *(uint4*)&tl[0];
        *(uint4*)(Vtl + off + 8) = *(uint4*)&tl[8];
        return;
    }

    int idx = (bx - VT_BLKS) * 256 + t;
    if (idx < RN0) {
        // ---- job0: q1 roped in place
        int s = idx / 768, pp = idx - s * 768;
        int col = pp << 1, i = pp & 31;
        float* bp = p.q1 + (size_t)s * DIM + col;
        float x0 = bp[0], x1 = bp[1];
        float c00, c01, c10, c11;
        pe_load(p.pe, dt, (size_t)s * 128 + i * 4, c00, c01, c10, c11);
        bp[0] = c00 * x0 + c01 * x1;
        bp[1] = c10 * x0 + c11 * x1;
        return;
    }
    idx -= RN0;
    if (idx < RN1) {
        // ---- job1: k1 roped -> khC/kloC split planes
        int s = idx / 768, pp = idx - s * 768;
        int col = pp << 1, i = pp & 31;
        float2 xv = *(const float2*)(p.k1 + (size_t)s * DIM + col);
        float c00, c01, c10, c11;
        pe_load(p.pe, dt, (size_t)s * 128 + i * 4, c00, c01, c10, c11);
        float y0 = c00 * xv.x + c01 * xv.y;
        float y1 = c10 * xv.x + c11 * xv.y;
        ushort h0 = f2bf(y0), h1 = f2bf(y1);
        ushort l0 = f2bf(y0 - bf2f(h0)), l1 = f2bf(y1 - bf2f(h1));
        *(unsigned int*)(p.khC  + (size_t)s * DIM + col) = (unsigned int)h0 | ((unsigned int)h1 << 16);
        *(unsigned int*)(p.kloC + (size_t)s * DIM + col) = (unsigned int)l0 | ((unsigned int)l1 << 16);
        return;
    }
    idx -= RN1;
    if (idx < RN2) {
        // ---- job2: i2q (original dtype) roped -> qx f32
        int s = idx / 768, pp = idx - s * 768;
        int col = pp << 1, i = pp & 31;
        float x0, x1;
        if (dt) {
            float2 xv = *(const float2*)((const float*)p.i2q + (size_t)s * DIM + col);
            x0 = xv.x; x1 = xv.y;
        } else {
            const ushort* sp = (const ushort*)p.i2q + (size_t)s * DIM + col;
            x0 = bf2f(sp[0]); x1 = bf2f(sp[1]);
        }
        float c00, c01, c10, c11;
        pe_load(p.pe, dt, (size_t)s * 128 + i * 4, c00, c01, c10, c11);
        float* dp = p.qx + (size_t)s * DIM + col;
        dp[0] = c00 * x0 + c01 * x1;
        dp[1] = c10 * x0 + c11 * x1;
    }
}

// ---------------------------------------------------------------------------
// MFMA flash attention, all three attentions (A-self, C-self, X-cross) in one
// launch. grid (56, NH, 2): x<20 seg A, x<40 seg C, else seg X. KV-split z=2,
// unnormalized partials + (m,l).
// ---------------------------------------------------------------------------
__device__ __forceinline__ int swz(int row, int col) {
    return row * 64 + ((((col >> 3) ^ row) & 7) << 3) + (col & 7);
}
__device__ __forceinline__ short8 ldfrag(const ushort* plane, int row, int col) {
    return *(const short8*)&plane[swz(row, col)];
}

struct AttnAllP {
    const float* Qf[3];
    const ushort* Kh[3]; const ushort* Kl[3];
    const ushort* Vth[3]; const ushort* Vtl[3];
    float* Op0[3]; float* Op1[3];
    float2* Ml[3];
    int mlq[3];       // SEQ, SEQ, IMG
};

__global__ __launch_bounds__(256) void attn_all(AttnAllP p)
{
    __shared__ ushort Qh_[4096], Ql_[4096];
    __shared__ ushort Kh_[4096], Kl_[4096];
    __shared__ ushort Vh_[4096], Vl_[4096];

    const int bx = blockIdx.x;
    const int seg = (bx < 20) ? 0 : (bx < 40) ? 1 : 2;
    const int q0 = (bx - ((seg == 0) ? 0 : (seg == 1) ? 20 : 40)) * 64;
    const int h = blockIdx.y;
    const int z = blockIdx.z;
    const int t = threadIdx.x;
    const int wave = t >> 6, lane = t & 63;
    const int quad = lane >> 4, l16 = lane & 15;
    const int wq0 = wave * 16;

    const float* Qf = p.Qf[seg];
    const ushort* Kh = p.Kh[seg]; const ushort* Kl = p.Kl[seg];
    const ushort* Vth = p.Vth[seg]; const ushort* Vtl = p.Vtl[seg];

    const int srow = t >> 2, c0 = (t & 3) << 4;
    const int g0 = c0 >> 3;
    const int p0 = ((g0 ^ (srow & 7)) & 7) << 3;
    const int p1 = (((g0 + 1) ^ (srow & 7)) & 7) << 3;

    {
        const float* src = Qf + (size_t)(q0 + srow) * DIM + h * HD + c0;
        float x[16];
        *(float4*)&x[0]  = *(const float4*)(src);
        *(float4*)&x[4]  = *(const float4*)(src + 4);
        *(float4*)&x[8]  = *(const float4*)(src + 8);
        *(float4*)&x[12] = *(const float4*)(src + 12);
        ushort hi[16], lo[16];
#pragma unroll
        for (int i = 0; i < 16; ++i) {
            hi[i] = f2bf(x[i]);
            lo[i] = f2bf(x[i] - bf2f(hi[i]));
        }
        *(uint4*)&Qh_[srow * 64 + p0] = *(uint4*)&hi[0];
        *(uint4*)&Qh_[srow * 64 + p1] = *(uint4*)&hi[8];
        *(uint4*)&Ql_[srow * 64 + p0] = *(uint4*)&lo[0];
        *(uint4*)&Ql_[srow * 64 + p1] = *(uint4*)&lo[8];
    }
    // Within-wave store->read (wave w stages rows 16w..16w+15; no barrier).
    short8 qfh[2], qfl[2];
#pragma unroll
    for (int c = 0; c < 2; ++c) {
        qfh[c] = ldfrag(Qh_, wq0 + l16, c * 32 + quad * 8);
        qfl[c] = ldfrag(Ql_, wq0 + l16, c * 32 + quad * 8);
    }

    float m_[4], l_[4];
#pragma unroll
    for (int r = 0; r < 4; ++r) { m_[r] = -3e38f; l_[r] = 0.0f; }
    f32x4 Oacc[4];
#pragma unroll
    for (int j = 0; j < 4; ++j) Oacc[j] = (f32x4)(0.0f);

    const int kvbeg = z * (SEQ / 2);
    for (int kt = 0; kt < SEQ / 2; kt += 64) {
        const int kv0 = kvbeg + kt;
        __syncthreads();
        {
            const size_t off = (size_t)(kv0 + srow) * DIM + h * HD + c0;
            *(uint4*)&Kh_[srow * 64 + p0] = *(const uint4*)(Kh + off);
            *(uint4*)&Kh_[srow * 64 + p1] = *(const uint4*)(Kh + off + 8);
            *(uint4*)&Kl_[srow * 64 + p0] = *(const uint4*)(Kl + off);
            *(uint4*)&Kl_[srow * 64 + p1] = *(const uint4*)(Kl + off + 8);
        }
        {
            const size_t off = (size_t)(h * HD + srow) * SEQ + kv0 + c0;
            *(uint4*)&Vh_[srow * 64 + p0] = *(const uint4*)(Vth + off);
            *(uint4*)&Vh_[srow * 64 + p1] = *(const uint4*)(Vth + off + 8);
            *(uint4*)&Vl_[srow * 64 + p0] = *(const uint4*)(Vtl + off);
            *(uint4*)&Vl_[srow * 64 + p1] = *(const uint4*)(Vtl + off + 8);
        }
        __syncthreads();

        f32x4 S[4];
#pragma unroll
        for (int j = 0; j < 4; ++j) S[j] = (f32x4)(0.0f);
        __builtin_amdgcn_s_setprio(1);
#pragma unroll
        for (int c = 0; c < 2; ++c) {
#pragma unroll
            for (int j = 0; j < 4; ++j) {
                short8 bh = ldfrag(Kh_, j * 16 + l16, c * 32 + quad * 8);
                short8 bl = ldfrag(Kl_, j * 16 + l16, c * 32 + quad * 8);
                S[j] = __builtin_amdgcn_mfma_f32_16x16x32_bf16(qfh[c], bh, S[j], 0, 0, 0);
                S[j] = __builtin_amdgcn_mfma_f32_16x16x32_bf16(qfl[c], bh, S[j], 0, 0, 0);
                S[j] = __builtin_amdgcn_mfma_f32_16x16x32_bf16(qfh[c], bl, S[j], 0, 0, 0);
            }
        }
        __builtin_amdgcn_s_setprio(0);
#pragma unroll
        for (int j = 0; j < 4; ++j)
#pragma unroll
            for (int r = 0; r < 4; ++r) S[j][r] *= 0.125f;

        float alpha[4];
#pragma unroll
        for (int r = 0; r < 4; ++r) {
            float mx = fmaxf(fmaxf(S[0][r], S[1][r]), fmaxf(S[2][r], S[3][r]));
            mx = fmaxf(mx, __shfl_xor(mx, 1));
            mx = fmaxf(mx, __shfl_xor(mx, 2));
            mx = fmaxf(mx, __shfl_xor(mx, 4));
            mx = fmaxf(mx, __shfl_xor(mx, 8));
            float mn = fmaxf(m_[r], mx);
            alpha[r] = __expf(m_[r] - mn);
            m_[r] = mn;
            float rs = 0.0f;
#pragma unroll
            for (int j = 0; j < 4; ++j) {
                float pv = __expf(S[j][r] - mn);
                S[j][r] = pv;
                rs += pv;
            }
            rs += __shfl_xor(rs, 1);
            rs += __shfl_xor(rs, 2);
            rs += __shfl_xor(rs, 4);
            rs += __shfl_xor(rs, 8);
            l_[r] = l_[r] * alpha[r] + rs;
        }
#pragma unroll
        for (int j = 0; j < 4; ++j)
#pragma unroll
            for (int r = 0; r < 4; ++r) Oacc[j][r] *= alpha[r];

        {
            const int prow = wq0 + quad * 4;
#pragma unroll
            for (int j = 0; j < 4; ++j)
#pragma unroll
                for (int r = 0; r < 4; ++r) {
                    float pv = S[j][r];
                    ushort ph = f2bf(pv);
                    ushort pl = f2bf(pv - bf2f(ph));
                    int idx = swz(prow + r, j * 16 + l16);
                    Qh_[idx] = ph;
                    Ql_[idx] = pl;
                }
        }

        __builtin_amdgcn_s_setprio(1);
#pragma unroll
        for (int c = 0; c < 2; ++c) {
            short8 pah = ldfrag(Qh_, wq0 + l16, c * 32 + quad * 8);
            short8 pal = ldfrag(Ql_, wq0 + l16, c * 32 + quad * 8);
#pragma unroll
            for (int jn = 0; jn < 4; ++jn) {
                short8 vbh = ldfrag(Vh_, jn * 16 + l16, c * 32 + quad * 8);
                short8 vbl = ldfrag(Vl_, jn * 16 + l16, c * 32 + quad * 8);
                Oacc[jn] = __builtin_amdgcn_mfma_f32_16x16x32_bf16(pah, vbh, Oacc[jn], 0, 0, 0);
                Oacc[jn] = __builtin_amdgcn_mfma_f32_16x16x32_bf16(pal, vbh, Oacc[jn], 0, 0, 0);
                Oacc[jn] = __builtin_amdgcn_mfma_f32_16x16x32_bf16(pah, vbl, Oacc[jn], 0, 0, 0);
            }
        }
        __builtin_amdgcn_s_setprio(0);
    }

    float* Opz = z ? p.Op1[seg] : p.Op0[seg];
    const int mlq = p.mlq[seg];
    float2* Ml = p.Ml[seg];
#pragma unroll
    for (int r = 0; r < 4; ++r) {
        const int rowq = q0 + wq0 + quad * 4 + r;
        if (l16 == 0)
            Ml[((size_t)z * NH + h) * mlq + rowq] = make_float2(m_[r], l_[r]);
#pragma unroll
        for (int jn = 0; jn < 4; ++jn)
            Opz[(size_t)rowq * DIM + h * HD + jn * 16 + l16] = Oacc[jn][r];
    }
}

// ---------------------------------------------------------------------------
// Unified merge: combines z-partials for A/C/X, folds cross residual into A
// (img rows), emits the out-proj A operand as bf16 hi/lo planes (2560 rows).
// ---------------------------------------------------------------------------
struct MergeP {
    const float *pA0, *pA1, *pC0, *pC1, *pX0, *pX1;
    const float2 *MlA, *MlC, *MlX;
    ushort *Xh, *Xl;
};

__device__ __forceinline__ float4 comb2(const float* O0, const float* O1,
                                        const float2* Ml, int mlq, int row, int c4)
{
    const int h = c4 >> 6;
    const float2 a = Ml[(size_t)h * mlq + row];
    const float2 b = Ml[(size_t)(NH + h) * mlq + row];
    const float ms = fmaxf(a.x, b.x);
    const float s0 = __expf(a.x - ms), s1 = __expf(b.x - ms);
    const float inv = 1.0f / (s0 * a.y + s1 * b.y);
    const float4 o0 = *(const float4*)&O0[(size_t)row * DIM + c4];
    const float4 o1 = *(const float4*)&O1[(size_t)row * DIM + c4];
    float4 r;
    r.x = (s0 * o0.x + s1 * o1.x) * inv;
    r.y = (s0 * o0.y + s1 * o1.y) * inv;
    r.z = (s0 * o0.z + s1 * o1.z) * inv;
    r.w = (s0 * o0.w + s1 * o1.w) * inv;
    return r;
}

__global__ __launch_bounds__(256) void merge_all(MergeP p)
{
    const int idx = blockIdx.x * 256 + threadIdx.x;
    if (idx >= 2560 * 384) return;
    const int row = idx / 384;
    const int c4 = (idx - row * 384) << 2;
    float4 r;
    if (row < SEQ) {
        r = comb2(p.pA0, p.pA1, p.MlA, SEQ, row, c4);
        if (row < IMG) {
            const float4 x = comb2(p.pX0, p.pX1, p.MlX, IMG, row, c4);
            r.x += x.x; r.y += x.y; r.z += x.z; r.w += x.w;
        }
    } else {
        r = comb2(p.pC0, p.pC1, p.MlC, SEQ, row - SEQ, c4);
    }
    float v[4] = {r.x, r.y, r.z, r.w};
    ushort hi[4], lo[4];
#pragma unroll
    for (int j = 0; j < 4; ++j) {
        hi[j] = f2bf(v[j]);
        lo[j] = f2bf(v[j] - bf2f(hi[j]));
    }
    const size_t o = (size_t)row * DIM + c4;
    *(uint2*)(p.Xh + o) = *(uint2*)hi;
    *(uint2*)(p.Xl + o) = *(uint2*)lo;
}

// ---------------------------------------------------------------------------
extern "C" void kernel_launch(void* const* d_in, const int* in_sizes, int n_in,
                              void* d_out, int out_size, void* d_ws, size_t ws_size,
                              hipStream_t stream) {
    (void)in_sizes; (void)n_in; (void)out_size; (void)ws_size;
    const void* hs   = d_in[0];
    const void* ehs  = d_in[1];
    const void* hsc  = d_in[2];
    const void* ehsc = d_in[3];
    const void* i2q  = d_in[4];
    const void* pe   = d_in[5];
#define W_(i) ((const void*)d_in[i])

    // ---- workspace layout (all sizes multiples of 256 B) ----
    char* base = (char*)d_ws;
    int* flag = (int*)base;
    char* ptr = base + 256;
    auto alloc = [&](size_t bytes) { char* r = ptr; ptr += bytes; return r; };
    float* q1  = (float*)alloc(SD * 4);      // C q f32 (roped inplace); later Xl
    float* k1  = (float*)alloc(SD * 4);      // C k f32; later pA1
    float* v1  = (float*)alloc(SD * 4);      // A v f32; later pA0
    float* vC  = (float*)alloc(SD * 4);      // C v f32; later pC0
    float* qA  = (float*)alloc(SD * 4);      // A q f32; later Xh
    float* qx  = (float*)alloc(IDSZ * 4);    // X q f32
    ushort* khA  = (ushort*)alloc(SD * 2);
    ushort* kloA = (ushort*)alloc(SD * 2);
    ushort* vthA = (ushort*)alloc(SD * 2);
    ushort* vtlA = (ushort*)alloc(SD * 2);
    ushort* khC  = (ushort*)alloc(SD * 2);
    ushort* kloC = (ushort*)alloc(SD * 2);
    ushort* vthC = (ushort*)alloc(SD * 2);
    ushort* vtlC = (ushort*)alloc(SD * 2);
    float* pX0 = (float*)alloc(IDSZ * 4);
    float* pX1 = (float*)alloc(IDSZ * 4);
    float2* MlA = (float2*)alloc((size_t)2 * NH * SEQ * 8);
    float2* MlC = (float2*)alloc((size_t)2 * NH * SEQ * 8);
    float2* MlX = (float2*)alloc((size_t)2 * NH * IMG * 8);
    ushort* Wbf = (ushort*)alloc(16 * WSZ * 2);   // 12 qkv + 4 out weights
    ushort* Xbf = (ushort*)alloc(2 * SD * 2);     // bf16 X; later pC1
    float* pC1 = (float*)Xbf;                      // dead after qkv
    ushort* Xh = (ushort*)qA;                      // dead after attn_all
    ushort* Xl = (ushort*)q1;                      // dead after attn_all

    dim3 blk(256);
    detect_dtype<<<1, blk, 0, stream>>>(hs, flag);

    // ---- one-time bf16 conversion: 16 weights + 4 X inputs ----
    {
        CvtP cp;
        const int wsrc[16] = {6, 8, 10, 12, 14, 16, 22, 24, 26, 28, 30, 32,
                              18, 20, 34, 36};
        for (int j = 0; j < 16; ++j) {
            cp.src[j] = W_(wsrc[j]);
            cp.dst[j] = Wbf + (size_t)j * WSZ;
            cp.n8[j] = (int)(WSZ / 8);
        }
        cp.src[16] = hs;   cp.dst[16] = Xbf;             cp.n8[16] = (int)(IDSZ / 8);
        cp.src[17] = ehs;  cp.dst[17] = Xbf + IDSZ;      cp.n8[17] = (int)((size_t)TXT * DIM / 8);
        cp.src[18] = hsc;  cp.dst[18] = Xbf + SD;        cp.n8[18] = (int)(IDSZ / 8);
        cp.src[19] = ehsc; cp.dst[19] = Xbf + SD + IDSZ; cp.n8[19] = (int)((size_t)TXT * DIM / 8);
        convert_bf16<<<dim3((int)(WSZ / 8 + 255) / 256, 20), blk, 0, stream>>>(cp, flag);
    }

    // ---- merged QKV for both streams ----
    QKV3P qp;
    qp.Xb = Xbf;
    qp.Wb = Wbf;
    {
        const int bsrc[12] = {7, 9, 11, 13, 15, 17, 23, 25, 27, 29, 31, 33};
        for (int j = 0; j < 12; ++j) qp.B[j] = W_(bsrc[j]);
    }
    for (int j = 0; j < 6; ++j) { qp.Y[j] = nullptr; qp.Yh[j] = nullptr; qp.Yl[j] = nullptr; }
    qp.Y[0] = qA;                      // A q f32
    qp.Yh[1] = khA; qp.Yl[1] = kloA;   // A k split planes
    qp.Y[2] = v1;                      // A v f32
    qp.Y[3] = q1;                      // C q f32
    qp.Y[4] = k1;                      // C k f32
    qp.Y[5] = vC;                      // C v f32
    gemm_qkv_v4<<<dim3(36, 20), blk, 0, stream>>>(qp, flag);

    // ---- fused prep: vtrans A+C, rope q1 inplace, k1->khC splits, i2q->qx ----
    {
        PrepP pp;
        pp.v1 = v1; pp.vC = vC;
        pp.vthA = vthA; pp.vtlA = vtlA; pp.vthC = vthC; pp.vtlC = vtlC;
        pp.q1 = q1;
        pp.k1 = k1; pp.khC = khC; pp.kloC = kloC;
        pp.i2q = i2q; pp.qx = qx;
        pp.pe = pe;
        const int ropeBlocks = (RN0 + RN1 + RN2 + 255) / 256;
        prep_fused<<<VT_BLKS + ropeBlocks, blk, 0, stream>>>(pp, flag);
    }

    // ---- all three attentions, one launch ----
    {
        AttnAllP ap;
        ap.Qf[0] = qA; ap.Qf[1] = q1; ap.Qf[2] = qx;
        ap.Kh[0] = khA; ap.Kl[0] = kloA;
        ap.Kh[1] = khC; ap.Kl[1] = kloC;
        ap.Kh[2] = khC; ap.Kl[2] = kloC;
        ap.Vth[0] = vthA; ap.Vtl[0] = vtlA;
        ap.Vth[1] = vthC; ap.Vtl[1] = vtlC;
        ap.Vth[2] = vthC; ap.Vtl[2] = vtlC;
        ap.Op0[0] = v1;  ap.Op1[0] = k1;    // A partials (v1,k1 dead)
        ap.Op0[1] = vC;  ap.Op1[1] = pC1;   // C partials (vC dead, Xbf dead)
        ap.Op0[2] = pX0; ap.Op1[2] = pX1;
        ap.Ml[0] = MlA; ap.Ml[1] = MlC; ap.Ml[2] = MlX;
        ap.mlq[0] = SEQ; ap.mlq[1] = SEQ; ap.mlq[2] = IMG;
        attn_all<<<dim3(56, NH, 2), blk, 0, stream>>>(ap);
    }

    // ---- unified merge -> bf16 hi/lo out-proj operand (2560 rows) ----
    {
        MergeP mp;
        mp.pA0 = v1; mp.pA1 = k1;
        mp.pC0 = vC; mp.pC1 = pC1;
        mp.pX0 = pX0; mp.pX1 = pX1;
        mp.MlA = MlA; mp.MlC = MlC; mp.MlX = MlX;
        mp.Xh = Xh; mp.Xl = Xl;
        merge_all<<<(2560 * 384 + 255) / 256, blk, 0, stream>>>(mp);
    }

    // ---- output projections ----
    {
        OutP op;
        op.Xh = Xh; op.Xl = Xl;
        op.Wb = Wbf + (size_t)12 * WSZ;
        op.B[0] = W_(19); op.B[1] = W_(21); op.B[2] = W_(35); op.B[3] = W_(37);
        op.out = d_out;
        gemm_out_v4<<<dim3(12, 40), blk, 0, stream>>>(op, flag);
    }
#undef W_
}